// Round 5
// baseline (2609.610 us; speedup 1.0000x reference)
//
#include <hip/hip_runtime.h>

#define RG_ITERS 12
#define RG_S 64
#define RG_IN 128
#define RG_H 16
#define RG_OUT 8
#define RG_BN_EPS 1e-5
#define RG_IN_THRESH 2e-3f   // f32 screen gap threshold, input layer (err bound ~1e-5)
#define RG_IT_THRESH 5e-4f   // f32 screen gap threshold, recurrent layer (err bound ~2e-5)

// ---------------------------------------------------------------------------
// Detect whether edge_index buffer is int64 (odd int32 words all zero) or int32
// ---------------------------------------------------------------------------
__global__ void detect_i64_kernel(const unsigned int* __restrict__ ei32, int* __restrict__ flag) {
    if (blockIdx.x == 0 && threadIdx.x == 0) {
        int allz = 1;
        for (int i = 1; i < 64; i += 2) allz &= (ei32[i] == 0u);
        *flag = allz;  // 1 -> int64, 0 -> int32
    }
}

__device__ __forceinline__ int load_edge(const void* ei, int is64, long long idx) {
    return is64 ? (int)((const long long*)ei)[idx] : ((const int*)ei)[idx];
}

// Compact edge list to int32 src/dst streams (handles i64 or i32 input)
__global__ void compact_kernel(const void* __restrict__ ei, const int* __restrict__ flag,
                               int* __restrict__ srcs, int* __restrict__ dsts, int E) {
    int is64 = *flag;
    int stride = gridDim.x * blockDim.x;
    for (int i = blockIdx.x * blockDim.x + threadIdx.x; i < E; i += stride) {
        srcs[i] = load_edge(ei, is64, i);
        dsts[i] = load_edge(ei, is64, (long long)E + i);
    }
}

// ---------------------------------------------------------------------------
// CSR build, L2-windowed: class r = blockIdx&7 (round-robin -> XCD r) owns
// dst range [r*span, (r+1)*span). Scatter targets stay in that XCD's L2.
// ---------------------------------------------------------------------------
__global__ __launch_bounds__(256) void deg2_kernel(const int* __restrict__ dsts,
                                                   int* __restrict__ deg, int E, int N) {
    int r = blockIdx.x & 7;
    int nb = gridDim.x >> 3;
    int bi = blockIdx.x >> 3;
    int span = (N + 7) >> 3;
    int lo = r * span;
    int hi = lo + span; hi = hi < N ? hi : N;
    int stride = nb * 256;
    for (int i = bi * 256 + threadIdx.x; i < E; i += stride) {
        int d = dsts[i];
        if (d >= lo && d < hi) atomicAdd(&deg[d], 1);
    }
}

__global__ __launch_bounds__(256) void fill2_kernel(const int* __restrict__ srcs,
                                                    const int* __restrict__ dsts,
                                                    int* __restrict__ cursor,
                                                    int* __restrict__ adj, int E, int N) {
    int r = blockIdx.x & 7;
    int nb = gridDim.x >> 3;
    int bi = blockIdx.x >> 3;
    int span = (N + 7) >> 3;
    int lo = r * span;
    int hi = lo + span; hi = hi < N ? hi : N;
    int stride = nb * 256;
    for (int i = bi * 256 + threadIdx.x; i < E; i += stride) {
        int d = dsts[i];
        if (d >= lo && d < hi) {
            int p = atomicAdd(&cursor[d], 1);
            adj[p] = srcs[i];  // row order nondeterministic; counting is order-invariant
        }
    }
}

// per-256-chunk sums
__global__ __launch_bounds__(256) void scanA_kernel(const int* __restrict__ deg,
                                                    int* __restrict__ bsum, int n) {
    int i = blockIdx.x * 256 + threadIdx.x;
    int v = (i < n) ? deg[i] : 0;
#pragma unroll
    for (int off = 32; off; off >>= 1) v += __shfl_xor(v, off);
    __shared__ int ws[4];
    if ((threadIdx.x & 63) == 0) ws[threadIdx.x >> 6] = v;
    __syncthreads();
    if (threadIdx.x == 0) bsum[blockIdx.x] = ws[0] + ws[1] + ws[2] + ws[3];
}

// exclusive scan of block sums, single block w/ carry loop
__global__ __launch_bounds__(512) void scanB_kernel(int* __restrict__ bsum,
                                                    int* __restrict__ row_off, int nb, int n) {
    __shared__ int buf[512];
    __shared__ int carry;
    int tid = threadIdx.x;
    if (tid == 0) carry = 0;
    __syncthreads();
    for (int base = 0; base < nb; base += 512) {
        int i = base + tid;
        int v = (i < nb) ? bsum[i] : 0;
        buf[tid] = v;
        __syncthreads();
        for (int off = 1; off < 512; off <<= 1) {
            int t = (tid >= off) ? buf[tid - off] : 0;
            __syncthreads();
            buf[tid] += t;
            __syncthreads();
        }
        if (i < nb) bsum[i] = carry + buf[tid] - v;  // exclusive
        __syncthreads();
        if (tid == 0) carry += buf[511];
        __syncthreads();
    }
    if (tid == 0) row_off[n] = carry;  // total edge count
}

// re-scan each 256-chunk, add block offset, emit row_off + cursor
__global__ __launch_bounds__(256) void scanC_kernel(const int* __restrict__ deg,
                                                    const int* __restrict__ bsum,
                                                    int* __restrict__ row_off,
                                                    int* __restrict__ cursor, int n) {
    __shared__ int buf[256];
    int tid = threadIdx.x;
    int i = blockIdx.x * 256 + tid;
    int v = (i < n) ? deg[i] : 0;
    buf[tid] = v;
    __syncthreads();
    for (int off = 1; off < 256; off <<= 1) {
        int t = (tid >= off) ? buf[tid - off] : 0;
        __syncthreads();
        buf[tid] += t;
        __syncthreads();
    }
    if (i < n) {
        int e = bsum[blockIdx.x] + buf[tid] - v;
        row_off[i] = e;
        cursor[i] = e;
    }
}

// ---------------------------------------------------------------------------
// Wave top-2 merge butterfly: returns (v1,i1,v2) identical in all lanes.
// Tie-break: smaller index wins top1 (matches jnp.argmax). XOR butterfly
// merges disjoint lane sets, so no double counting.
// ---------------------------------------------------------------------------
__device__ __forceinline__ void top2_f32(float y, int lane, float& v1, int& i1, float& v2) {
    v1 = y; i1 = lane; v2 = -3.4e38f;
#pragma unroll
    for (int off = 32; off; off >>= 1) {
        float ov1 = __shfl_xor(v1, off);
        int oi1 = __shfl_xor(i1, off);
        float ov2 = __shfl_xor(v2, off);
        bool take = (ov1 > v1) || (ov1 == v1 && oi1 < i1);
        float nv2 = take ? fmaxf(v1, ov2) : fmaxf(v2, ov1);
        v1 = take ? ov1 : v1;
        i1 = take ? oi1 : i1;
        v2 = nv2;
    }
}

__device__ __forceinline__ int argmax_f64(double y, int lane) {
    double best = y;
    int bi = lane;
#pragma unroll
    for (int off = 32; off; off >>= 1) {
        double ov = __shfl_xor(best, off);
        int oi = __shfl_xor(bi, off);
        if (ov > best || (ov == best && oi < bi)) { best = ov; bi = oi; }
    }
    return bi;
}

// ---------------------------------------------------------------------------
// Input layer: state0[n] = argmax_j ( x[n,:] @ W_in[:,j] + b_in[j] )
// f32 screening pass (8 chains) + exact f64 fallback when top-2 gap < THRESH
// ---------------------------------------------------------------------------
__global__ __launch_bounds__(256) void input_kernel(const float* __restrict__ x,
                                                    const float* __restrict__ W_in,
                                                    const float* __restrict__ b_in,
                                                    unsigned char* __restrict__ st, int n) {
    __shared__ float wsh[RG_IN * RG_S];  // 32 KB
    for (int i = threadIdx.x; i < RG_IN * RG_S; i += 256) wsh[i] = W_in[i];
    __syncthreads();
    int lane = threadIdx.x & 63;
    int wid = threadIdx.x >> 6;
    float binf = b_in[lane];
    double bind = (double)binf;
    int stride = gridDim.x * 4;
    for (int node = blockIdx.x * 4 + wid; node < n; node += stride) {
        const float4* xr = (const float4*)(x + (size_t)node * RG_IN);
        // ---- f32 screen: 8 independent chains over 32 float4 steps ----
        float f0 = 0.f, f1 = 0.f, f2 = 0.f, f3 = 0.f, f4 = 0.f, f5 = 0.f, f6 = 0.f, f7 = 0.f;
#pragma unroll 4
        for (int k4 = 0; k4 < RG_IN / 4; k4 += 2) {
            float4 xa = xr[k4];
            float4 xb = xr[k4 + 1];
            int ka = k4 * 4, kb = k4 * 4 + 4;
            f0 += xa.x * wsh[(ka + 0) * RG_S + lane];
            f1 += xa.y * wsh[(ka + 1) * RG_S + lane];
            f2 += xa.z * wsh[(ka + 2) * RG_S + lane];
            f3 += xa.w * wsh[(ka + 3) * RG_S + lane];
            f4 += xb.x * wsh[(kb + 0) * RG_S + lane];
            f5 += xb.y * wsh[(kb + 1) * RG_S + lane];
            f6 += xb.z * wsh[(kb + 2) * RG_S + lane];
            f7 += xb.w * wsh[(kb + 3) * RG_S + lane];
        }
        float yf = (((f0 + f4) + (f1 + f5)) + ((f2 + f6) + (f3 + f7))) + binf;
        float v1, v2;
        int i1;
        top2_f32(yf, lane, v1, i1, v2);
        int st_res = i1;
        if (v1 - v2 < RG_IN_THRESH) {  // wave-uniform: exact f64 redo (rare)
            double a0 = 0.0, a1 = 0.0, a2 = 0.0, a3 = 0.0;
#pragma unroll 8
            for (int k4 = 0; k4 < RG_IN / 4; ++k4) {
                float4 xv = xr[k4];
                int k = k4 * 4;
                a0 += (double)xv.x * (double)wsh[(k + 0) * RG_S + lane];
                a1 += (double)xv.y * (double)wsh[(k + 1) * RG_S + lane];
                a2 += (double)xv.z * (double)wsh[(k + 2) * RG_S + lane];
                a3 += (double)xv.w * (double)wsh[(k + 3) * RG_S + lane];
            }
            double acc = bind + ((a0 + a2) + (a1 + a3));
            st_res = argmax_f64(acc, lane);
        }
        if (lane == 0) st[node] = (unsigned char)st_res;
    }
}

// ---------------------------------------------------------------------------
// One recurrent iteration — ballot histogram, nibble-packed counts,
// f32 screening matvec (4 chains) + exact f64 fallback on top-2 gap < THRESH
// ---------------------------------------------------------------------------
__global__ __launch_bounds__(256) void iter_kernel(const int* __restrict__ row_off,
                                                   const int* __restrict__ adj,
                                                   const unsigned char* __restrict__ st_in,
                                                   unsigned char* __restrict__ st_out,
                                                   const float* __restrict__ W_rec,
                                                   const float* __restrict__ b_rec,
                                                   const float* __restrict__ bn_g,
                                                   const float* __restrict__ bn_b,
                                                   const float* __restrict__ bn_m,
                                                   const float* __restrict__ bn_v, int n) {
    int lane = threadIdx.x & 63;
    int wid = threadIdx.x >> 6;

    float wcol[RG_S];  // column `lane` of W_rec first half, statically indexed
#pragma unroll
    for (int k = 0; k < RG_S; ++k) wcol[k] = W_rec[k * RG_S + lane];
    double brec = (double)b_rec[lane];
    double bnm = (double)bn_m[lane];
    double bns = (double)bn_g[lane] / sqrt((double)bn_v[lane] + RG_BN_EPS);
    double bnb = (double)bn_b[lane];
    float brecf = (float)brec, bnmf = (float)bnm, bnsf = (float)bns, bnbf = (float)bnb;

    int stride = gridDim.x * 4;
    for (int node = blockIdx.x * 4 + wid; node < n; node += stride) {
        int beg = row_off[node], end = row_off[node + 1];
        int st_old = (int)st_in[node];                         // issue early
        float wself = W_rec[(RG_S + st_old) * RG_S + lane];    // L1-resident, hidden by gather
        int cnt = 0;  // exact count of in-neighbors with state == lane
        for (int base = beg; base < end; base += 64) {
            int idx = base + lane;
            unsigned long long valid = __ballot(idx < end);
            int sv = (idx < end) ? (int)st_in[adj[idx]] : 0;
            unsigned long long mm = valid;
#pragma unroll
            for (int b = 0; b < 6; ++b) {
                unsigned long long bl = __ballot(((sv >> b) & 1) != 0);
                mm &= ((lane >> b) & 1) ? bl : ~bl;
            }
            cnt += (int)__popcll(mm);
        }
        // clamp to 10 (fits a nibble), butterfly-pack all 64 counts into pk[8]
        unsigned v = (cnt > 10) ? 10u : (unsigned)cnt;
        unsigned p;
        p = __shfl_xor(v, 1);  v = (lane & 1) ? (p | (v << 4))  : (v | (p << 4));
        p = __shfl_xor(v, 2);  v = (lane & 2) ? (p | (v << 8))  : (v | (p << 8));
        p = __shfl_xor(v, 4);  v = (lane & 4) ? (p | (v << 16)) : (v | (p << 16));
        unsigned q0, q1;
        p = __shfl_xor(v, 8);
        q0 = (lane & 8) ? p : v;  q1 = (lane & 8) ? v : p;
        unsigned r0 = __shfl_xor(q0, 16), r1 = __shfl_xor(q1, 16);
        unsigned s0, s1, s2, s3;
        if (lane & 16) { s0 = r0; s1 = r1; s2 = q0; s3 = q1; }
        else           { s0 = q0; s1 = q1; s2 = r0; s3 = r1; }
        unsigned t0 = __shfl_xor(s0, 32), t1 = __shfl_xor(s1, 32),
                 t2 = __shfl_xor(s2, 32), t3 = __shfl_xor(s3, 32);
        unsigned pk[8];
        if (lane & 32) { pk[0]=t0; pk[1]=t1; pk[2]=t2; pk[3]=t3; pk[4]=s0; pk[5]=s1; pk[6]=s2; pk[7]=s3; }
        else           { pk[0]=s0; pk[1]=s1; pk[2]=s2; pk[3]=s3; pk[4]=t0; pk[5]=t1; pk[6]=t2; pk[7]=t3; }

#define RG_CNT(k) ((pk[(k) >> 3] >> (((k) & 7) * 4)) & 0xFu)
        // ---- f32 screen: 4 independent chains ----
        float zf0 = 0.f, zf1 = 0.f, zf2 = 0.f, zf3 = 0.f;
#pragma unroll
        for (int k = 0; k < RG_S; k += 4) {
            zf0 += (float)RG_CNT(k + 0) * wcol[k + 0];
            zf1 += (float)RG_CNT(k + 1) * wcol[k + 1];
            zf2 += (float)RG_CNT(k + 2) * wcol[k + 2];
            zf3 += (float)RG_CNT(k + 3) * wcol[k + 3];
        }
        float zf = (((zf0 + zf2) + (zf1 + zf3))) + brecf + wself;
        float yff = (zf - bnmf) * bnsf + bnbf;
        float v1, v2;
        int i1;
        top2_f32(yff, lane, v1, i1, v2);
        int st_res = i1;
        if (v1 - v2 < RG_IT_THRESH) {  // wave-uniform: exact f64 redo (rare)
            double z0 = 0.0, z1 = 0.0, z2 = 0.0, z3 = 0.0;
#pragma unroll
            for (int k = 0; k < RG_S; k += 4) {
                z0 += (double)RG_CNT(k + 0) * (double)wcol[k + 0];
                z1 += (double)RG_CNT(k + 1) * (double)wcol[k + 1];
                z2 += (double)RG_CNT(k + 2) * (double)wcol[k + 2];
                z3 += (double)RG_CNT(k + 3) * (double)wcol[k + 3];
            }
            double z = ((z0 + z2) + (z1 + z3)) + brec + (double)wself;
            double y = (z - bnm) * bns + bnb;
            st_res = argmax_f64(y, lane);
        }
#undef RG_CNT
        if (lane == 0) st_out[node] = (unsigned char)st_res;
    }
}

// ---------------------------------------------------------------------------
// Output MLP collapses to a 64x8 lookup table over the final state
// ---------------------------------------------------------------------------
__global__ void table_kernel(const float* __restrict__ Wo1, const float* __restrict__ bo1,
                             const float* __restrict__ g, const float* __restrict__ b,
                             const float* __restrict__ m, const float* __restrict__ v,
                             const float* __restrict__ Wo2, const float* __restrict__ bo2,
                             float* __restrict__ table) {
    int k = threadIdx.x;
    if (k >= RG_S) return;
    double h[RG_H];
#pragma unroll
    for (int j = 0; j < RG_H; ++j) {
        double z = (double)Wo1[k * RG_H + j] + (double)bo1[j];
        double y = (z - (double)m[j]) * ((double)g[j] / sqrt((double)v[j] + RG_BN_EPS)) +
                   (double)b[j];
        h[j] = y > 0.0 ? y : 0.0;
    }
#pragma unroll
    for (int o = 0; o < RG_OUT; ++o) {
        double acc = (double)bo2[o];
#pragma unroll
        for (int j = 0; j < RG_H; ++j) acc += h[j] * (double)Wo2[j * RG_OUT + o];
        table[k * RG_OUT + o] = (float)acc;
    }
}

__global__ void out_kernel(const unsigned char* __restrict__ st, const float* __restrict__ table,
                           float* __restrict__ out, int n) {
    int i = blockIdx.x * blockDim.x + threadIdx.x;
    if (i >= n) return;
    int s = (int)st[i];
    float4 a = ((const float4*)table)[s * 2];
    float4 b = ((const float4*)table)[s * 2 + 1];
    ((float4*)out)[(size_t)i * 2] = a;
    ((float4*)out)[(size_t)i * 2 + 1] = b;
}

// ---------------------------------------------------------------------------
extern "C" void kernel_launch(void* const* d_in, const int* in_sizes, int n_in,
                              void* d_out, int out_size, void* d_ws, size_t ws_size,
                              hipStream_t stream) {
    const float* x     = (const float*)d_in[0];
    const void*  ei    = d_in[1];
    const float* W_in  = (const float*)d_in[2];
    const float* b_in  = (const float*)d_in[3];
    const float* W_rec = (const float*)d_in[4];
    const float* b_rec = (const float*)d_in[5];
    const float* bn_g  = (const float*)d_in[6];
    const float* bn_b  = (const float*)d_in[7];
    const float* bn_m  = (const float*)d_in[8];
    const float* bn_v  = (const float*)d_in[9];
    const float* Wo1   = (const float*)d_in[10];
    const float* bo1   = (const float*)d_in[11];
    const float* bno_g = (const float*)d_in[12];
    const float* bno_b = (const float*)d_in[13];
    const float* bno_m = (const float*)d_in[14];
    const float* bno_v = (const float*)d_in[15];
    const float* Wo2   = (const float*)d_in[16];
    const float* bo2   = (const float*)d_in[17];

    int N = in_sizes[0] / RG_IN;
    int E = in_sizes[1] / 2;

    char* ws = (char*)d_ws;
    size_t off = 0;
    auto alloc = [&](size_t bytes) -> void* {
        void* p = ws + off;
        off = (off + bytes + 255) & ~(size_t)255;
        return p;
    };
    int nchunks = (N + 255) / 256;
    int*           flag    = (int*)alloc(sizeof(int));
    int*           deg     = (int*)alloc((size_t)N * sizeof(int));
    int*           row_off = (int*)alloc((size_t)(N + 1) * sizeof(int));
    int*           cursor  = (int*)alloc((size_t)N * sizeof(int));
    int*           adj     = (int*)alloc((size_t)E * sizeof(int));
    int*           srcs    = (int*)alloc((size_t)E * sizeof(int));
    int*           dsts    = (int*)alloc((size_t)E * sizeof(int));
    int*           bsum    = (int*)alloc((size_t)nchunks * sizeof(int));
    unsigned char* stA     = (unsigned char*)alloc((size_t)N);
    unsigned char* stB     = (unsigned char*)alloc((size_t)N);
    float*         table   = (float*)alloc(RG_S * RG_OUT * sizeof(float));

    hipMemsetAsync(deg, 0, (size_t)N * sizeof(int), stream);
    detect_i64_kernel<<<1, 64, 0, stream>>>((const unsigned int*)ei, flag);

    compact_kernel<<<2048, 256, 0, stream>>>(ei, flag, srcs, dsts, E);
    deg2_kernel<<<4096, 256, 0, stream>>>(dsts, deg, E, N);
    scanA_kernel<<<nchunks, 256, 0, stream>>>(deg, bsum, N);
    scanB_kernel<<<1, 512, 0, stream>>>(bsum, row_off, nchunks, N);
    scanC_kernel<<<nchunks, 256, 0, stream>>>(deg, bsum, row_off, cursor, N);
    fill2_kernel<<<4096, 256, 0, stream>>>(srcs, dsts, cursor, adj, E, N);

    input_kernel<<<1280, 256, 0, stream>>>(x, W_in, b_in, stA, N);

    unsigned char* sin = stA;
    unsigned char* sout = stB;
    for (int it = 0; it < RG_ITERS; ++it) {
        iter_kernel<<<1024, 256, 0, stream>>>(row_off, adj, sin, sout, W_rec, b_rec, bn_g, bn_b,
                                              bn_m, bn_v, N);
        unsigned char* t = sin; sin = sout; sout = t;
    }

    table_kernel<<<1, 64, 0, stream>>>(Wo1, bo1, bno_g, bno_b, bno_m, bno_v, Wo2, bo2, table);
    out_kernel<<<(N + 255) / 256, 256, 0, stream>>>(sin, table, (float*)d_out, N);
}

// Round 6
// 1268.078 us; speedup vs baseline: 2.0579x; 2.0579x over previous
//
#include <hip/hip_runtime.h>

#define RG_ITERS 12
#define RG_S 64
#define RG_IN 128
#define RG_H 16
#define RG_OUT 8
#define RG_BN_EPS 1e-5
#define RG_IN_THRESH 2e-3f   // f32 screen gap threshold, input layer (err bound ~1e-5)
#define RG_IT_THRESH 5e-4f   // f32 screen gap threshold, recurrent layer (err bound ~2e-5)

// ---------------------------------------------------------------------------
// Detect whether edge_index buffer is int64 (odd int32 words all zero) or int32
// ---------------------------------------------------------------------------
__global__ void detect_i64_kernel(const unsigned int* __restrict__ ei32, int* __restrict__ flag) {
    if (blockIdx.x == 0 && threadIdx.x == 0) {
        int allz = 1;
        for (int i = 1; i < 64; i += 2) allz &= (ei32[i] == 0u);
        *flag = allz;  // 1 -> int64, 0 -> int32
    }
}

__device__ __forceinline__ int load_edge(const void* ei, int is64, long long idx) {
    return is64 ? (int)((const long long*)ei)[idx] : ((const int*)ei)[idx];
}

// Compact edge list to int32 src/dst streams (handles i64 or i32 input)
__global__ void compact_kernel(const void* __restrict__ ei, const int* __restrict__ flag,
                               int* __restrict__ srcs, int* __restrict__ dsts, int E) {
    int is64 = *flag;
    int stride = gridDim.x * blockDim.x;
    for (int i = blockIdx.x * blockDim.x + threadIdx.x; i < E; i += stride) {
        srcs[i] = load_edge(ei, is64, i);
        dsts[i] = load_edge(ei, is64, (long long)E + i);
    }
}

// ---------------------------------------------------------------------------
// CSR build, L2-windowed: class r = blockIdx&7 (round-robin -> XCD r) owns
// dst range [r*span, (r+1)*span). Scatter targets stay in that XCD's L2.
// ---------------------------------------------------------------------------
__global__ __launch_bounds__(256) void deg2_kernel(const int* __restrict__ dsts,
                                                   int* __restrict__ deg, int E, int N) {
    int r = blockIdx.x & 7;
    int nb = gridDim.x >> 3;
    int bi = blockIdx.x >> 3;
    int span = (N + 7) >> 3;
    int lo = r * span;
    int hi = lo + span; hi = hi < N ? hi : N;
    int stride = nb * 256;
    for (int i = bi * 256 + threadIdx.x; i < E; i += stride) {
        int d = dsts[i];
        if (d >= lo && d < hi) atomicAdd(&deg[d], 1);
    }
}

__global__ __launch_bounds__(256) void fill2_kernel(const int* __restrict__ srcs,
                                                    const int* __restrict__ dsts,
                                                    int* __restrict__ cursor,
                                                    int* __restrict__ adj, int E, int N) {
    int r = blockIdx.x & 7;
    int nb = gridDim.x >> 3;
    int bi = blockIdx.x >> 3;
    int span = (N + 7) >> 3;
    int lo = r * span;
    int hi = lo + span; hi = hi < N ? hi : N;
    int stride = nb * 256;
    for (int i = bi * 256 + threadIdx.x; i < E; i += stride) {
        int d = dsts[i];
        if (d >= lo && d < hi) {
            int p = atomicAdd(&cursor[d], 1);
            adj[p] = srcs[i];  // row order nondeterministic; counting is order-invariant
        }
    }
}

// per-256-chunk sums
__global__ __launch_bounds__(256) void scanA_kernel(const int* __restrict__ deg,
                                                    int* __restrict__ bsum, int n) {
    int i = blockIdx.x * 256 + threadIdx.x;
    int v = (i < n) ? deg[i] : 0;
#pragma unroll
    for (int off = 32; off; off >>= 1) v += __shfl_xor(v, off);
    __shared__ int ws[4];
    if ((threadIdx.x & 63) == 0) ws[threadIdx.x >> 6] = v;
    __syncthreads();
    if (threadIdx.x == 0) bsum[blockIdx.x] = ws[0] + ws[1] + ws[2] + ws[3];
}

// exclusive scan of block sums, single block w/ carry loop
__global__ __launch_bounds__(512) void scanB_kernel(int* __restrict__ bsum,
                                                    int* __restrict__ row_off, int nb, int n) {
    __shared__ int buf[512];
    __shared__ int carry;
    int tid = threadIdx.x;
    if (tid == 0) carry = 0;
    __syncthreads();
    for (int base = 0; base < nb; base += 512) {
        int i = base + tid;
        int v = (i < nb) ? bsum[i] : 0;
        buf[tid] = v;
        __syncthreads();
        for (int off = 1; off < 512; off <<= 1) {
            int t = (tid >= off) ? buf[tid - off] : 0;
            __syncthreads();
            buf[tid] += t;
            __syncthreads();
        }
        if (i < nb) bsum[i] = carry + buf[tid] - v;  // exclusive
        __syncthreads();
        if (tid == 0) carry += buf[511];
        __syncthreads();
    }
    if (tid == 0) row_off[n] = carry;  // total edge count
}

// re-scan each 256-chunk, add block offset, emit row_off + cursor
__global__ __launch_bounds__(256) void scanC_kernel(const int* __restrict__ deg,
                                                    const int* __restrict__ bsum,
                                                    int* __restrict__ row_off,
                                                    int* __restrict__ cursor, int n) {
    __shared__ int buf[256];
    int tid = threadIdx.x;
    int i = blockIdx.x * 256 + tid;
    int v = (i < n) ? deg[i] : 0;
    buf[tid] = v;
    __syncthreads();
    for (int off = 1; off < 256; off <<= 1) {
        int t = (tid >= off) ? buf[tid - off] : 0;
        __syncthreads();
        buf[tid] += t;
        __syncthreads();
    }
    if (i < n) {
        int e = bsum[blockIdx.x] + buf[tid] - v;
        row_off[i] = e;
        cursor[i] = e;
    }
}

// ---------------------------------------------------------------------------
// Wave top-2 merge butterfly: returns (v1,i1,v2) identical in all lanes.
// Tie-break: smaller index wins top1 (matches jnp.argmax).
// ---------------------------------------------------------------------------
__device__ __forceinline__ void top2_f32(float y, int lane, float& v1, int& i1, float& v2) {
    v1 = y; i1 = lane; v2 = -3.4e38f;
#pragma unroll
    for (int off = 32; off; off >>= 1) {
        float ov1 = __shfl_xor(v1, off);
        int oi1 = __shfl_xor(i1, off);
        float ov2 = __shfl_xor(v2, off);
        bool take = (ov1 > v1) || (ov1 == v1 && oi1 < i1);
        float nv2 = take ? fmaxf(v1, ov2) : fmaxf(v2, ov1);
        v1 = take ? ov1 : v1;
        i1 = take ? oi1 : i1;
        v2 = nv2;
    }
}

__device__ __forceinline__ int argmax_f64(double y, int lane) {
    double best = y;
    int bi = lane;
#pragma unroll
    for (int off = 32; off; off >>= 1) {
        double ov = __shfl_xor(best, off);
        int oi = __shfl_xor(bi, off);
        if (ov > best || (ov == best && oi < bi)) { best = ov; bi = oi; }
    }
    return bi;
}

// ---------------------------------------------------------------------------
// Ballot histogram: cnt = #in-neighbors with state == lane, clamped to 10
// ---------------------------------------------------------------------------
__device__ __forceinline__ int hist_count(const int* __restrict__ adj,
                                          const unsigned char* __restrict__ st_in,
                                          int beg, int end, int lane) {
    int cnt = 0;
    for (int base = beg; base < end; base += 64) {
        int idx = base + lane;
        unsigned long long valid = __ballot(idx < end);
        int sv = (idx < end) ? (int)st_in[adj[idx]] : 0;
        unsigned long long mm = valid;
#pragma unroll
        for (int b = 0; b < 6; ++b) {
            unsigned long long bl = __ballot(((sv >> b) & 1) != 0);
            mm &= ((lane >> b) & 1) ? bl : ~bl;
        }
        cnt += (int)__popcll(mm);
    }
    return cnt > 10 ? 10 : cnt;
}

// Byte butterfly pack: per-lane count -> pk[16], pk[g] bytes0..3 = cnt[4g..4g+3]
__device__ __forceinline__ void pack_bytes(unsigned cmin, int lane, unsigned pk[16]) {
    unsigned v = cmin, p;
    p = __shfl_xor(v, 1); v = (lane & 1) ? (p | (v << 8)) : (v | (p << 8));
    p = __shfl_xor(v, 2); v = (lane & 2) ? (p | (v << 16)) : (v | (p << 16));
    unsigned q0, q1;
    p = __shfl_xor(v, 4); q0 = (lane & 4) ? p : v; q1 = (lane & 4) ? v : p;
    unsigned r0 = __shfl_xor(q0, 8), r1 = __shfl_xor(q1, 8);
    unsigned u0, u1, u2, u3;
    if (lane & 8) { u0 = r0; u1 = r1; u2 = q0; u3 = q1; }
    else          { u0 = q0; u1 = q1; u2 = r0; u3 = r1; }
    unsigned w0 = __shfl_xor(u0, 16), w1 = __shfl_xor(u1, 16),
             w2 = __shfl_xor(u2, 16), w3 = __shfl_xor(u3, 16);
    unsigned a0, a1, a2, a3, a4, a5, a6, a7;
    if (lane & 16) { a0 = w0; a1 = w1; a2 = w2; a3 = w3; a4 = u0; a5 = u1; a6 = u2; a7 = u3; }
    else           { a0 = u0; a1 = u1; a2 = u2; a3 = u3; a4 = w0; a5 = w1; a6 = w2; a7 = w3; }
    unsigned b0 = __shfl_xor(a0, 32), b1 = __shfl_xor(a1, 32), b2 = __shfl_xor(a2, 32),
             b3 = __shfl_xor(a3, 32), b4 = __shfl_xor(a4, 32), b5 = __shfl_xor(a5, 32),
             b6 = __shfl_xor(a6, 32), b7 = __shfl_xor(a7, 32);
    if (lane & 32) {
        pk[0] = b0; pk[1] = b1; pk[2] = b2; pk[3] = b3;
        pk[4] = b4; pk[5] = b5; pk[6] = b6; pk[7] = b7;
        pk[8] = a0; pk[9] = a1; pk[10] = a2; pk[11] = a3;
        pk[12] = a4; pk[13] = a5; pk[14] = a6; pk[15] = a7;
    } else {
        pk[0] = a0; pk[1] = a1; pk[2] = a2; pk[3] = a3;
        pk[4] = a4; pk[5] = a5; pk[6] = a6; pk[7] = a7;
        pk[8] = b0; pk[9] = b1; pk[10] = b2; pk[11] = b3;
        pk[12] = b4; pk[13] = b5; pk[14] = b6; pk[15] = b7;
    }
}

// ---------------------------------------------------------------------------
// Input layer: state0[n] = argmax_j ( x[n,:] @ W_in[:,j] + b_in[j] )
// f32 screening pass (8 chains) + exact f64 fallback when top-2 gap < THRESH
// ---------------------------------------------------------------------------
__global__ __launch_bounds__(256) void input_kernel(const float* __restrict__ x,
                                                    const float* __restrict__ W_in,
                                                    const float* __restrict__ b_in,
                                                    unsigned char* __restrict__ st, int n) {
    __shared__ float wsh[RG_IN * RG_S];  // 32 KB
    for (int i = threadIdx.x; i < RG_IN * RG_S; i += 256) wsh[i] = W_in[i];
    __syncthreads();
    int lane = threadIdx.x & 63;
    int wid = threadIdx.x >> 6;
    float binf = b_in[lane];
    double bind = (double)binf;
    int stride = gridDim.x * 4;
    for (int node = blockIdx.x * 4 + wid; node < n; node += stride) {
        const float4* xr = (const float4*)(x + (size_t)node * RG_IN);
        float f0 = 0.f, f1 = 0.f, f2 = 0.f, f3 = 0.f, f4 = 0.f, f5 = 0.f, f6 = 0.f, f7 = 0.f;
#pragma unroll 4
        for (int k4 = 0; k4 < RG_IN / 4; k4 += 2) {
            float4 xa = xr[k4];
            float4 xb = xr[k4 + 1];
            int ka = k4 * 4, kb = k4 * 4 + 4;
            f0 += xa.x * wsh[(ka + 0) * RG_S + lane];
            f1 += xa.y * wsh[(ka + 1) * RG_S + lane];
            f2 += xa.z * wsh[(ka + 2) * RG_S + lane];
            f3 += xa.w * wsh[(ka + 3) * RG_S + lane];
            f4 += xb.x * wsh[(kb + 0) * RG_S + lane];
            f5 += xb.y * wsh[(kb + 1) * RG_S + lane];
            f6 += xb.z * wsh[(kb + 2) * RG_S + lane];
            f7 += xb.w * wsh[(kb + 3) * RG_S + lane];
        }
        float yf = (((f0 + f4) + (f1 + f5)) + ((f2 + f6) + (f3 + f7))) + binf;
        float v1, v2;
        int i1;
        top2_f32(yf, lane, v1, i1, v2);
        int st_res = i1;
        if (v1 - v2 < RG_IN_THRESH) {  // wave-uniform: exact f64 redo (rare)
            double a0 = 0.0, a1 = 0.0, a2 = 0.0, a3 = 0.0;
#pragma unroll 8
            for (int k4 = 0; k4 < RG_IN / 4; ++k4) {
                float4 xv = xr[k4];
                int k = k4 * 4;
                a0 += (double)xv.x * (double)wsh[(k + 0) * RG_S + lane];
                a1 += (double)xv.y * (double)wsh[(k + 1) * RG_S + lane];
                a2 += (double)xv.z * (double)wsh[(k + 2) * RG_S + lane];
                a3 += (double)xv.w * (double)wsh[(k + 3) * RG_S + lane];
            }
            double acc = bind + ((a0 + a2) + (a1 + a3));
            st_res = argmax_f64(acc, lane);
        }
        if (lane == 0) st[node] = (unsigned char)st_res;
    }
}

// ---------------------------------------------------------------------------
// Recurrent iteration, phase 1 (hot): f32 screen only.
// BN pre-folded into weights: wcol[k] = W_rec[k][lane]*s, bias/self scaled.
// Ambiguous waves (top-2 gap < THRESH) append node to list for phase 2.
// ---------------------------------------------------------------------------
__global__ __launch_bounds__(256) void iter_screen_kernel(
    const int* __restrict__ row_off, const int* __restrict__ adj,
    const unsigned char* __restrict__ st_in, unsigned char* __restrict__ st_out,
    const float* __restrict__ W_rec, const float* __restrict__ b_rec,
    const float* __restrict__ bn_g, const float* __restrict__ bn_b,
    const float* __restrict__ bn_m, const float* __restrict__ bn_v,
    int* __restrict__ amb_cnt, int* __restrict__ amb_list, int n) {
    int lane = threadIdx.x & 63;
    int wid = threadIdx.x >> 6;

    float s = bn_g[lane] * rsqrtf(bn_v[lane] + 1e-5f);
    float biasp = b_rec[lane] * s + (bn_b[lane] - bn_m[lane] * s);
    float wcol[RG_S];
#pragma unroll
    for (int k = 0; k < RG_S; ++k) wcol[k] = W_rec[k * RG_S + lane] * s;

    int stride = gridDim.x * 4;
    for (int node = blockIdx.x * 4 + wid; node < n; node += stride) {
        int beg = row_off[node], end = row_off[node + 1];
        int st_old = (int)st_in[node];
        float wself = W_rec[(RG_S + st_old) * RG_S + lane] * s;  // L1-hot, hidden by gather
        int cmin = hist_count(adj, st_in, beg, end, lane);
        unsigned pk[16];
        pack_bytes((unsigned)cmin, lane, pk);

        float y0 = 0.f, y1 = 0.f, y2 = 0.f, y3 = 0.f;
#pragma unroll
        for (int g = 0; g < 16; ++g) {
            unsigned pg = pk[g];
            y0 += (float)(pg & 0xFFu)         * wcol[4 * g + 0];
            y1 += (float)((pg >> 8) & 0xFFu)  * wcol[4 * g + 1];
            y2 += (float)((pg >> 16) & 0xFFu) * wcol[4 * g + 2];
            y3 += (float)(pg >> 24)           * wcol[4 * g + 3];
        }
        float y = ((y0 + y2) + (y1 + y3)) + biasp + wself;

        float v1, v2;
        int i1;
        top2_f32(y, lane, v1, i1, v2);
        if (lane == 0) {
            st_out[node] = (unsigned char)i1;
            if (v1 - v2 < RG_IT_THRESH) {
                int pidx = atomicAdd(amb_cnt, 1);
                amb_list[pidx] = node;  // phase 2 overwrites st_out[node]
            }
        }
    }
}

// ---------------------------------------------------------------------------
// Recurrent iteration, phase 2 (rare): exact f64 recompute for listed nodes.
// Identical math/order to the previously passing inline f64 fallback.
// ---------------------------------------------------------------------------
__global__ __launch_bounds__(256) void iter_fix_kernel(
    const int* __restrict__ amb_cnt, const int* __restrict__ amb_list,
    const int* __restrict__ row_off, const int* __restrict__ adj,
    const unsigned char* __restrict__ st_in, unsigned char* __restrict__ st_out,
    const float* __restrict__ W_rec, const float* __restrict__ b_rec,
    const float* __restrict__ bn_g, const float* __restrict__ bn_b,
    const float* __restrict__ bn_m, const float* __restrict__ bn_v) {
    int tot = *amb_cnt;
    if (tot <= 0) return;
    int lane = threadIdx.x & 63;
    int wid = threadIdx.x >> 6;
    double brec = (double)b_rec[lane];
    double bnm = (double)bn_m[lane];
    double bns = (double)bn_g[lane] / sqrt((double)bn_v[lane] + RG_BN_EPS);
    double bnb = (double)bn_b[lane];
    int nw = gridDim.x * 4;
    for (int li = blockIdx.x * 4 + wid; li < tot; li += nw) {
        int node = amb_list[li];
        int beg = row_off[node], end = row_off[node + 1];
        int st_old = (int)st_in[node];
        float wself = W_rec[(RG_S + st_old) * RG_S + lane];
        int cmin = hist_count(adj, st_in, beg, end, lane);
        unsigned pk[16];
        pack_bytes((unsigned)cmin, lane, pk);
        double z0 = 0.0, z1 = 0.0, z2 = 0.0, z3 = 0.0;
#pragma unroll
        for (int g = 0; g < 16; ++g) {
            unsigned pg = pk[g];
            z0 += (double)(pg & 0xFFu)         * (double)W_rec[(4 * g + 0) * RG_S + lane];
            z1 += (double)((pg >> 8) & 0xFFu)  * (double)W_rec[(4 * g + 1) * RG_S + lane];
            z2 += (double)((pg >> 16) & 0xFFu) * (double)W_rec[(4 * g + 2) * RG_S + lane];
            z3 += (double)(pg >> 24)           * (double)W_rec[(4 * g + 3) * RG_S + lane];
        }
        double z = ((z0 + z2) + (z1 + z3)) + brec + (double)wself;
        double y = (z - bnm) * bns + bnb;
        int st_res = argmax_f64(y, lane);
        if (lane == 0) st_out[node] = (unsigned char)st_res;
    }
}

// ---------------------------------------------------------------------------
// Output MLP collapses to a 64x8 lookup table over the final state
// ---------------------------------------------------------------------------
__global__ void table_kernel(const float* __restrict__ Wo1, const float* __restrict__ bo1,
                             const float* __restrict__ g, const float* __restrict__ b,
                             const float* __restrict__ m, const float* __restrict__ v,
                             const float* __restrict__ Wo2, const float* __restrict__ bo2,
                             float* __restrict__ table) {
    int k = threadIdx.x;
    if (k >= RG_S) return;
    double h[RG_H];
#pragma unroll
    for (int j = 0; j < RG_H; ++j) {
        double z = (double)Wo1[k * RG_H + j] + (double)bo1[j];
        double y = (z - (double)m[j]) * ((double)g[j] / sqrt((double)v[j] + RG_BN_EPS)) +
                   (double)b[j];
        h[j] = y > 0.0 ? y : 0.0;
    }
#pragma unroll
    for (int o = 0; o < RG_OUT; ++o) {
        double acc = (double)bo2[o];
#pragma unroll
        for (int j = 0; j < RG_H; ++j) acc += h[j] * (double)Wo2[j * RG_OUT + o];
        table[k * RG_OUT + o] = (float)acc;
    }
}

__global__ void out_kernel(const unsigned char* __restrict__ st, const float* __restrict__ table,
                           float* __restrict__ out, int n) {
    int i = blockIdx.x * blockDim.x + threadIdx.x;
    if (i >= n) return;
    int s = (int)st[i];
    float4 a = ((const float4*)table)[s * 2];
    float4 b = ((const float4*)table)[s * 2 + 1];
    ((float4*)out)[(size_t)i * 2] = a;
    ((float4*)out)[(size_t)i * 2 + 1] = b;
}

// ---------------------------------------------------------------------------
extern "C" void kernel_launch(void* const* d_in, const int* in_sizes, int n_in,
                              void* d_out, int out_size, void* d_ws, size_t ws_size,
                              hipStream_t stream) {
    const float* x     = (const float*)d_in[0];
    const void*  ei    = d_in[1];
    const float* W_in  = (const float*)d_in[2];
    const float* b_in  = (const float*)d_in[3];
    const float* W_rec = (const float*)d_in[4];
    const float* b_rec = (const float*)d_in[5];
    const float* bn_g  = (const float*)d_in[6];
    const float* bn_b  = (const float*)d_in[7];
    const float* bn_m  = (const float*)d_in[8];
    const float* bn_v  = (const float*)d_in[9];
    const float* Wo1   = (const float*)d_in[10];
    const float* bo1   = (const float*)d_in[11];
    const float* bno_g = (const float*)d_in[12];
    const float* bno_b = (const float*)d_in[13];
    const float* bno_m = (const float*)d_in[14];
    const float* bno_v = (const float*)d_in[15];
    const float* Wo2   = (const float*)d_in[16];
    const float* bo2   = (const float*)d_in[17];

    int N = in_sizes[0] / RG_IN;
    int E = in_sizes[1] / 2;

    char* ws = (char*)d_ws;
    size_t off = 0;
    auto alloc = [&](size_t bytes) -> void* {
        void* p = ws + off;
        off = (off + bytes + 255) & ~(size_t)255;
        return p;
    };
    int nchunks = (N + 255) / 256;
    int*           flag    = (int*)alloc(sizeof(int));
    int*           deg     = (int*)alloc((size_t)N * sizeof(int));
    int*           row_off = (int*)alloc((size_t)(N + 1) * sizeof(int));
    int*           cursor  = (int*)alloc((size_t)N * sizeof(int));
    int*           adj     = (int*)alloc((size_t)E * sizeof(int));
    int*           srcs    = (int*)alloc((size_t)E * sizeof(int));
    int*           dsts    = (int*)alloc((size_t)E * sizeof(int));
    int*           bsum    = (int*)alloc((size_t)nchunks * sizeof(int));
    unsigned char* stA     = (unsigned char*)alloc((size_t)N);
    unsigned char* stB     = (unsigned char*)alloc((size_t)N);
    int*           ambc    = (int*)alloc(RG_ITERS * sizeof(int));
    int*           ambl    = (int*)alloc((size_t)N * sizeof(int));
    float*         table   = (float*)alloc(RG_S * RG_OUT * sizeof(float));

    hipMemsetAsync(deg, 0, (size_t)N * sizeof(int), stream);
    hipMemsetAsync(ambc, 0, RG_ITERS * sizeof(int), stream);
    detect_i64_kernel<<<1, 64, 0, stream>>>((const unsigned int*)ei, flag);

    compact_kernel<<<2048, 256, 0, stream>>>(ei, flag, srcs, dsts, E);
    deg2_kernel<<<4096, 256, 0, stream>>>(dsts, deg, E, N);
    scanA_kernel<<<nchunks, 256, 0, stream>>>(deg, bsum, N);
    scanB_kernel<<<1, 512, 0, stream>>>(bsum, row_off, nchunks, N);
    scanC_kernel<<<nchunks, 256, 0, stream>>>(deg, bsum, row_off, cursor, N);
    fill2_kernel<<<4096, 256, 0, stream>>>(srcs, dsts, cursor, adj, E, N);

    input_kernel<<<1280, 256, 0, stream>>>(x, W_in, b_in, stA, N);

    unsigned char* sin = stA;
    unsigned char* sout = stB;
    for (int it = 0; it < RG_ITERS; ++it) {
        iter_screen_kernel<<<1024, 256, 0, stream>>>(row_off, adj, sin, sout, W_rec, b_rec,
                                                     bn_g, bn_b, bn_m, bn_v,
                                                     ambc + it, ambl, N);
        iter_fix_kernel<<<128, 256, 0, stream>>>(ambc + it, ambl, row_off, adj, sin, sout,
                                                 W_rec, b_rec, bn_g, bn_b, bn_m, bn_v);
        unsigned char* t = sin; sin = sout; sout = t;
    }

    table_kernel<<<1, 64, 0, stream>>>(Wo1, bo1, bno_g, bno_b, bno_m, bno_v, Wo2, bo2, table);
    out_kernel<<<(N + 255) / 256, 256, 0, stream>>>(sin, table, (float*)d_out, N);
}

// Round 7
// 1142.832 us; speedup vs baseline: 2.2835x; 1.1096x over previous
//
#include <hip/hip_runtime.h>

#define RG_ITERS 12
#define RG_S 64
#define RG_IN 128
#define RG_H 16
#define RG_OUT 8
#define RG_BN_EPS 1e-5
#define RG_IN_THRESH 2e-3f   // f32 screen gap threshold, input layer (err bound ~1e-5)
#define RG_IT_THRESH 5e-4f   // f32 screen gap threshold, recurrent layer (err bound ~2e-5)

// ---------------------------------------------------------------------------
// Detect whether edge_index buffer is int64 (odd int32 words all zero) or int32
// ---------------------------------------------------------------------------
__global__ void detect_i64_kernel(const unsigned int* __restrict__ ei32, int* __restrict__ flag) {
    if (blockIdx.x == 0 && threadIdx.x == 0) {
        int allz = 1;
        for (int i = 1; i < 64; i += 2) allz &= (ei32[i] == 0u);
        *flag = allz;  // 1 -> int64, 0 -> int32
    }
}

__device__ __forceinline__ int load_edge(const void* ei, int is64, long long idx) {
    return is64 ? (int)((const long long*)ei)[idx] : ((const int*)ei)[idx];
}

// Compact edge list to int32 src/dst streams (handles i64 or i32 input)
__global__ void compact_kernel(const void* __restrict__ ei, const int* __restrict__ flag,
                               int* __restrict__ srcs, int* __restrict__ dsts, int E) {
    int is64 = *flag;
    int stride = gridDim.x * blockDim.x;
    for (int i = blockIdx.x * blockDim.x + threadIdx.x; i < E; i += stride) {
        srcs[i] = load_edge(ei, is64, i);
        dsts[i] = load_edge(ei, is64, (long long)E + i);
    }
}

// ---------------------------------------------------------------------------
// CSR build, L2-windowed: class r = blockIdx&7 (round-robin -> XCD r) owns
// dst range [r*span, (r+1)*span). Scatter targets stay in that XCD's L2.
// ---------------------------------------------------------------------------
__global__ __launch_bounds__(256) void deg2_kernel(const int* __restrict__ dsts,
                                                   int* __restrict__ deg, int E, int N) {
    int r = blockIdx.x & 7;
    int nb = gridDim.x >> 3;
    int bi = blockIdx.x >> 3;
    int span = (N + 7) >> 3;
    int lo = r * span;
    int hi = lo + span; hi = hi < N ? hi : N;
    int stride = nb * 256;
    for (int i = bi * 256 + threadIdx.x; i < E; i += stride) {
        int d = dsts[i];
        if (d >= lo && d < hi) atomicAdd(&deg[d], 1);
    }
}

__global__ __launch_bounds__(256) void fill2_kernel(const int* __restrict__ srcs,
                                                    const int* __restrict__ dsts,
                                                    int* __restrict__ cursor,
                                                    int* __restrict__ adj, int E, int N) {
    int r = blockIdx.x & 7;
    int nb = gridDim.x >> 3;
    int bi = blockIdx.x >> 3;
    int span = (N + 7) >> 3;
    int lo = r * span;
    int hi = lo + span; hi = hi < N ? hi : N;
    int stride = nb * 256;
    for (int i = bi * 256 + threadIdx.x; i < E; i += stride) {
        int d = dsts[i];
        if (d >= lo && d < hi) {
            int p = atomicAdd(&cursor[d], 1);
            adj[p] = srcs[i];  // row order nondeterministic; counting is order-invariant
        }
    }
}

// per-256-chunk sums
__global__ __launch_bounds__(256) void scanA_kernel(const int* __restrict__ deg,
                                                    int* __restrict__ bsum, int n) {
    int i = blockIdx.x * 256 + threadIdx.x;
    int v = (i < n) ? deg[i] : 0;
#pragma unroll
    for (int off = 32; off; off >>= 1) v += __shfl_xor(v, off);
    __shared__ int ws[4];
    if ((threadIdx.x & 63) == 0) ws[threadIdx.x >> 6] = v;
    __syncthreads();
    if (threadIdx.x == 0) bsum[blockIdx.x] = ws[0] + ws[1] + ws[2] + ws[3];
}

// exclusive scan of block sums, single block w/ carry loop
__global__ __launch_bounds__(512) void scanB_kernel(int* __restrict__ bsum,
                                                    int* __restrict__ row_off, int nb, int n) {
    __shared__ int buf[512];
    __shared__ int carry;
    int tid = threadIdx.x;
    if (tid == 0) carry = 0;
    __syncthreads();
    for (int base = 0; base < nb; base += 512) {
        int i = base + tid;
        int v = (i < nb) ? bsum[i] : 0;
        buf[tid] = v;
        __syncthreads();
        for (int off = 1; off < 512; off <<= 1) {
            int t = (tid >= off) ? buf[tid - off] : 0;
            __syncthreads();
            buf[tid] += t;
            __syncthreads();
        }
        if (i < nb) bsum[i] = carry + buf[tid] - v;  // exclusive
        __syncthreads();
        if (tid == 0) carry += buf[511];
        __syncthreads();
    }
    if (tid == 0) row_off[n] = carry;  // total edge count
}

// re-scan each 256-chunk, add block offset, emit row_off + cursor
__global__ __launch_bounds__(256) void scanC_kernel(const int* __restrict__ deg,
                                                    const int* __restrict__ bsum,
                                                    int* __restrict__ row_off,
                                                    int* __restrict__ cursor, int n) {
    __shared__ int buf[256];
    int tid = threadIdx.x;
    int i = blockIdx.x * 256 + tid;
    int v = (i < n) ? deg[i] : 0;
    buf[tid] = v;
    __syncthreads();
    for (int off = 1; off < 256; off <<= 1) {
        int t = (tid >= off) ? buf[tid - off] : 0;
        __syncthreads();
        buf[tid] += t;
        __syncthreads();
    }
    if (i < n) {
        int e = bsum[blockIdx.x] + buf[tid] - v;
        row_off[i] = e;
        cursor[i] = e;
    }
}

// ---------------------------------------------------------------------------
// Wave top-2 merge butterfly: returns (v1,i1,v2) identical in all lanes.
// Tie-break: smaller index wins top1 (matches jnp.argmax).
// ---------------------------------------------------------------------------
__device__ __forceinline__ void top2_f32(float y, int lane, float& v1, int& i1, float& v2) {
    v1 = y; i1 = lane; v2 = -3.4e38f;
#pragma unroll
    for (int off = 32; off; off >>= 1) {
        float ov1 = __shfl_xor(v1, off);
        int oi1 = __shfl_xor(i1, off);
        float ov2 = __shfl_xor(v2, off);
        bool take = (ov1 > v1) || (ov1 == v1 && oi1 < i1);
        float nv2 = take ? fmaxf(v1, ov2) : fmaxf(v2, ov1);
        v1 = take ? ov1 : v1;
        i1 = take ? oi1 : i1;
        v2 = nv2;
    }
}

__device__ __forceinline__ int argmax_f64(double y, int lane) {
    double best = y;
    int bi = lane;
#pragma unroll
    for (int off = 32; off; off >>= 1) {
        double ov = __shfl_xor(best, off);
        int oi = __shfl_xor(bi, off);
        if (ov > best || (ov == best && oi < bi)) { best = ov; bi = oi; }
    }
    return bi;
}

// ---------------------------------------------------------------------------
// Ballot histogram: cnt = #in-neighbors with state == lane, clamped to 10
// ---------------------------------------------------------------------------
__device__ __forceinline__ int hist_count(const int* __restrict__ adj,
                                          const unsigned char* __restrict__ st_in,
                                          int beg, int end, int lane) {
    int cnt = 0;
    for (int base = beg; base < end; base += 64) {
        int idx = base + lane;
        unsigned long long valid = __ballot(idx < end);
        int sv = (idx < end) ? (int)st_in[adj[idx]] : 0;
        unsigned long long mm = valid;
#pragma unroll
        for (int b = 0; b < 6; ++b) {
            unsigned long long bl = __ballot(((sv >> b) & 1) != 0);
            mm &= ((lane >> b) & 1) ? bl : ~bl;
        }
        cnt += (int)__popcll(mm);
    }
    return cnt > 10 ? 10 : cnt;
}

// Byte butterfly pack (cold path only): count -> pk[16] bytes
__device__ __forceinline__ void pack_bytes(unsigned cmin, int lane, unsigned pk[16]) {
    unsigned v = cmin, p;
    p = __shfl_xor(v, 1); v = (lane & 1) ? (p | (v << 8)) : (v | (p << 8));
    p = __shfl_xor(v, 2); v = (lane & 2) ? (p | (v << 16)) : (v | (p << 16));
    unsigned q0, q1;
    p = __shfl_xor(v, 4); q0 = (lane & 4) ? p : v; q1 = (lane & 4) ? v : p;
    unsigned r0 = __shfl_xor(q0, 8), r1 = __shfl_xor(q1, 8);
    unsigned u0, u1, u2, u3;
    if (lane & 8) { u0 = r0; u1 = r1; u2 = q0; u3 = q1; }
    else          { u0 = q0; u1 = q1; u2 = r0; u3 = r1; }
    unsigned w0 = __shfl_xor(u0, 16), w1 = __shfl_xor(u1, 16),
             w2 = __shfl_xor(u2, 16), w3 = __shfl_xor(u3, 16);
    unsigned a0, a1, a2, a3, a4, a5, a6, a7;
    if (lane & 16) { a0 = w0; a1 = w1; a2 = w2; a3 = w3; a4 = u0; a5 = u1; a6 = u2; a7 = u3; }
    else           { a0 = u0; a1 = u1; a2 = u2; a3 = u3; a4 = w0; a5 = w1; a6 = w2; a7 = w3; }
    unsigned b0 = __shfl_xor(a0, 32), b1 = __shfl_xor(a1, 32), b2 = __shfl_xor(a2, 32),
             b3 = __shfl_xor(a3, 32), b4 = __shfl_xor(a4, 32), b5 = __shfl_xor(a5, 32),
             b6 = __shfl_xor(a6, 32), b7 = __shfl_xor(a7, 32);
    if (lane & 32) {
        pk[0] = b0; pk[1] = b1; pk[2] = b2; pk[3] = b3;
        pk[4] = b4; pk[5] = b5; pk[6] = b6; pk[7] = b7;
        pk[8] = a0; pk[9] = a1; pk[10] = a2; pk[11] = a3;
        pk[12] = a4; pk[13] = a5; pk[14] = a6; pk[15] = a7;
    } else {
        pk[0] = a0; pk[1] = a1; pk[2] = a2; pk[3] = a3;
        pk[4] = a4; pk[5] = a5; pk[6] = a6; pk[7] = a7;
        pk[8] = b0; pk[9] = b1; pk[10] = b2; pk[11] = b3;
        pk[12] = b4; pk[13] = b5; pk[14] = b6; pk[15] = b7;
    }
}

// ---------------------------------------------------------------------------
// Input layer: 4 nodes per wave iteration. Each LDS weight read feeds 4 FMAs
// (one per node); 16 independent f32 chains. f64 fallback per node if the
// top-2 gap < THRESH (rare, wave-uniform).
// ---------------------------------------------------------------------------
__device__ __forceinline__ int input_f64_node(const float4* __restrict__ xr,
                                              const float* __restrict__ wsh,
                                              double bind, int lane) {
    double a0 = 0.0, a1 = 0.0, a2 = 0.0, a3 = 0.0;
#pragma unroll 8
    for (int k4 = 0; k4 < RG_IN / 4; ++k4) {
        float4 xv = xr[k4];
        int k = k4 * 4;
        a0 += (double)xv.x * (double)wsh[(k + 0) * RG_S + lane];
        a1 += (double)xv.y * (double)wsh[(k + 1) * RG_S + lane];
        a2 += (double)xv.z * (double)wsh[(k + 2) * RG_S + lane];
        a3 += (double)xv.w * (double)wsh[(k + 3) * RG_S + lane];
    }
    double acc = bind + ((a0 + a2) + (a1 + a3));
    return argmax_f64(acc, lane);
}

__global__ __launch_bounds__(256) void input_kernel(const float* __restrict__ x,
                                                    const float* __restrict__ W_in,
                                                    const float* __restrict__ b_in,
                                                    unsigned char* __restrict__ st, int n) {
    __shared__ float wsh[RG_IN * RG_S];  // 32 KB
    for (int i = threadIdx.x; i < RG_IN * RG_S; i += 256) wsh[i] = W_in[i];
    __syncthreads();
    int lane = threadIdx.x & 63;
    int wid = threadIdx.x >> 6;
    float binf = b_in[lane];
    double bind = (double)binf;
    int wave = blockIdx.x * 4 + wid;
    int nwaves = gridDim.x * 4;
    int ngroups = (n + 3) >> 2;
    for (int g = wave; g < ngroups; g += nwaves) {
        int base = g * 4;
        int n0 = base;
        int n1 = base + 1 < n ? base + 1 : n - 1;
        int n2 = base + 2 < n ? base + 2 : n - 1;
        int n3 = base + 3 < n ? base + 3 : n - 1;
        const float4* x0 = (const float4*)(x + (size_t)n0 * RG_IN);
        const float4* x1 = (const float4*)(x + (size_t)n1 * RG_IN);
        const float4* x2 = (const float4*)(x + (size_t)n2 * RG_IN);
        const float4* x3 = (const float4*)(x + (size_t)n3 * RG_IN);
        float a00 = 0.f, a01 = 0.f, a02 = 0.f, a03 = 0.f;
        float a10 = 0.f, a11 = 0.f, a12 = 0.f, a13 = 0.f;
        float a20 = 0.f, a21 = 0.f, a22 = 0.f, a23 = 0.f;
        float a30 = 0.f, a31 = 0.f, a32 = 0.f, a33 = 0.f;
#pragma unroll 4
        for (int k4 = 0; k4 < RG_IN / 4; ++k4) {
            float4 v0 = x0[k4], v1 = x1[k4], v2 = x2[k4], v3 = x3[k4];
            int k = k4 * 4;
            float w0 = wsh[(k + 0) * RG_S + lane];
            float w1 = wsh[(k + 1) * RG_S + lane];
            float w2 = wsh[(k + 2) * RG_S + lane];
            float w3 = wsh[(k + 3) * RG_S + lane];
            a00 += v0.x * w0; a01 += v0.y * w1; a02 += v0.z * w2; a03 += v0.w * w3;
            a10 += v1.x * w0; a11 += v1.y * w1; a12 += v1.z * w2; a13 += v1.w * w3;
            a20 += v2.x * w0; a21 += v2.y * w1; a22 += v2.z * w2; a23 += v2.w * w3;
            a30 += v3.x * w0; a31 += v3.y * w1; a32 += v3.z * w2; a33 += v3.w * w3;
        }
        float y0 = ((a00 + a02) + (a01 + a03)) + binf;
        float y1 = ((a10 + a12) + (a11 + a13)) + binf;
        float y2 = ((a20 + a22) + (a21 + a23)) + binf;
        float y3 = ((a30 + a32) + (a31 + a33)) + binf;

        float v1f, v2f;
        int i1;
        top2_f32(y0, lane, v1f, i1, v2f);
        int s0 = (v1f - v2f < RG_IN_THRESH) ? input_f64_node(x0, wsh, bind, lane) : i1;
        top2_f32(y1, lane, v1f, i1, v2f);
        int s1 = (v1f - v2f < RG_IN_THRESH) ? input_f64_node(x1, wsh, bind, lane) : i1;
        top2_f32(y2, lane, v1f, i1, v2f);
        int s2 = (v1f - v2f < RG_IN_THRESH) ? input_f64_node(x2, wsh, bind, lane) : i1;
        top2_f32(y3, lane, v1f, i1, v2f);
        int s3 = (v1f - v2f < RG_IN_THRESH) ? input_f64_node(x3, wsh, bind, lane) : i1;
        if (lane == 0) {
            st[n0] = (unsigned char)s0;
            st[n1] = (unsigned char)s1;
            st[n2] = (unsigned char)s2;
            st[n3] = (unsigned char)s3;
        }
    }
}

// ---------------------------------------------------------------------------
// Recurrent iteration, phase 1 (hot): f32 screen, 2 nodes per wave iteration.
// Counts broadcast via per-wave LDS slot (no butterfly pack). BN pre-folded.
// Ambiguous waves append node to list for exact-f64 phase 2.
// ---------------------------------------------------------------------------
__global__ __launch_bounds__(256) void iter_screen_kernel(
    const int* __restrict__ row_off, const int* __restrict__ adj,
    const unsigned char* __restrict__ st_in, unsigned char* __restrict__ st_out,
    const float* __restrict__ W_rec, const float* __restrict__ b_rec,
    const float* __restrict__ bn_g, const float* __restrict__ bn_b,
    const float* __restrict__ bn_m, const float* __restrict__ bn_v,
    int* __restrict__ amb_cnt, int* __restrict__ amb_list, int n) {
    __shared__ unsigned int cslot[4][2][16];  // [wave][node A/B][64 byte counts]
    int lane = threadIdx.x & 63;
    int wid = threadIdx.x >> 6;

    float s = bn_g[lane] * rsqrtf(bn_v[lane] + 1e-5f);
    float biasp = b_rec[lane] * s + (bn_b[lane] - bn_m[lane] * s);
    float wcol[RG_S];
#pragma unroll
    for (int k = 0; k < RG_S; ++k) wcol[k] = W_rec[k * RG_S + lane] * s;

    unsigned char* slotA = (unsigned char*)&cslot[wid][0][0];
    unsigned char* slotB = (unsigned char*)&cslot[wid][1][0];

    int wave = blockIdx.x * 4 + wid;
    int nwaves = gridDim.x * 4;
    for (int nA = wave; nA < n; nA += 2 * nwaves) {
        int nB = nA + nwaves;
        bool hasB = nB < n;
        int begA = row_off[nA], endA = row_off[nA + 1];
        int stoA = (int)st_in[nA];
        float wselfA = W_rec[(RG_S + stoA) * RG_S + lane] * s;
        int begB = 0, endB = 0;
        float wselfB = 0.f;
        if (hasB) {
            begB = row_off[nB]; endB = row_off[nB + 1];
            int stoB = (int)st_in[nB];
            wselfB = W_rec[(RG_S + stoB) * RG_S + lane] * s;
        }
        int cA = hist_count(adj, st_in, begA, endA, lane);
        slotA[lane] = (unsigned char)cA;
        if (hasB) {
            int cB = hist_count(adj, st_in, begB, endB, lane);
            slotB[lane] = (unsigned char)cB;
        }
        // same-wave DS ordering: all lanes' byte writes precede these reads
        float yA0 = 0.f, yA1 = 0.f, yA2 = 0.f, yA3 = 0.f;
        float yB0 = 0.f, yB1 = 0.f, yB2 = 0.f, yB3 = 0.f;
#pragma unroll
        for (int g = 0; g < 16; ++g) {
            unsigned pA = cslot[wid][0][g];
            unsigned pB = cslot[wid][1][g];
            yA0 += (float)(pA & 0xFFu)         * wcol[4 * g + 0];
            yA1 += (float)((pA >> 8) & 0xFFu)  * wcol[4 * g + 1];
            yA2 += (float)((pA >> 16) & 0xFFu) * wcol[4 * g + 2];
            yA3 += (float)(pA >> 24)           * wcol[4 * g + 3];
            yB0 += (float)(pB & 0xFFu)         * wcol[4 * g + 0];
            yB1 += (float)((pB >> 8) & 0xFFu)  * wcol[4 * g + 1];
            yB2 += (float)((pB >> 16) & 0xFFu) * wcol[4 * g + 2];
            yB3 += (float)(pB >> 24)           * wcol[4 * g + 3];
        }
        float yA = ((yA0 + yA2) + (yA1 + yA3)) + biasp + wselfA;
        float v1, v2;
        int i1;
        top2_f32(yA, lane, v1, i1, v2);
        if (lane == 0) {
            st_out[nA] = (unsigned char)i1;
            if (v1 - v2 < RG_IT_THRESH) {
                int pidx = atomicAdd(amb_cnt, 1);
                amb_list[pidx] = nA;
            }
        }
        if (hasB) {
            float yB = ((yB0 + yB2) + (yB1 + yB3)) + biasp + wselfB;
            top2_f32(yB, lane, v1, i1, v2);
            if (lane == 0) {
                st_out[nB] = (unsigned char)i1;
                if (v1 - v2 < RG_IT_THRESH) {
                    int pidx = atomicAdd(amb_cnt, 1);
                    amb_list[pidx] = nB;
                }
            }
        }
    }
}

// ---------------------------------------------------------------------------
// Recurrent iteration, phase 2 (rare): exact f64 recompute for listed nodes.
// ---------------------------------------------------------------------------
__global__ __launch_bounds__(256) void iter_fix_kernel(
    const int* __restrict__ amb_cnt, const int* __restrict__ amb_list,
    const int* __restrict__ row_off, const int* __restrict__ adj,
    const unsigned char* __restrict__ st_in, unsigned char* __restrict__ st_out,
    const float* __restrict__ W_rec, const float* __restrict__ b_rec,
    const float* __restrict__ bn_g, const float* __restrict__ bn_b,
    const float* __restrict__ bn_m, const float* __restrict__ bn_v) {
    int tot = *amb_cnt;
    if (tot <= 0) return;
    int lane = threadIdx.x & 63;
    int wid = threadIdx.x >> 6;
    double brec = (double)b_rec[lane];
    double bnm = (double)bn_m[lane];
    double bns = (double)bn_g[lane] / sqrt((double)bn_v[lane] + RG_BN_EPS);
    double bnb = (double)bn_b[lane];
    int nw = gridDim.x * 4;
    for (int li = blockIdx.x * 4 + wid; li < tot; li += nw) {
        int node = amb_list[li];
        int beg = row_off[node], end = row_off[node + 1];
        int st_old = (int)st_in[node];
        float wself = W_rec[(RG_S + st_old) * RG_S + lane];
        int cmin = hist_count(adj, st_in, beg, end, lane);
        unsigned pk[16];
        pack_bytes((unsigned)cmin, lane, pk);
        double z0 = 0.0, z1 = 0.0, z2 = 0.0, z3 = 0.0;
#pragma unroll
        for (int g = 0; g < 16; ++g) {
            unsigned pg = pk[g];
            z0 += (double)(pg & 0xFFu)         * (double)W_rec[(4 * g + 0) * RG_S + lane];
            z1 += (double)((pg >> 8) & 0xFFu)  * (double)W_rec[(4 * g + 1) * RG_S + lane];
            z2 += (double)((pg >> 16) & 0xFFu) * (double)W_rec[(4 * g + 2) * RG_S + lane];
            z3 += (double)(pg >> 24)           * (double)W_rec[(4 * g + 3) * RG_S + lane];
        }
        double z = ((z0 + z2) + (z1 + z3)) + brec + (double)wself;
        double y = (z - bnm) * bns + bnb;
        int st_res = argmax_f64(y, lane);
        if (lane == 0) st_out[node] = (unsigned char)st_res;
    }
}

// ---------------------------------------------------------------------------
// Output MLP collapses to a 64x8 lookup table over the final state
// ---------------------------------------------------------------------------
__global__ void table_kernel(const float* __restrict__ Wo1, const float* __restrict__ bo1,
                             const float* __restrict__ g, const float* __restrict__ b,
                             const float* __restrict__ m, const float* __restrict__ v,
                             const float* __restrict__ Wo2, const float* __restrict__ bo2,
                             float* __restrict__ table) {
    int k = threadIdx.x;
    if (k >= RG_S) return;
    double h[RG_H];
#pragma unroll
    for (int j = 0; j < RG_H; ++j) {
        double z = (double)Wo1[k * RG_H + j] + (double)bo1[j];
        double y = (z - (double)m[j]) * ((double)g[j] / sqrt((double)v[j] + RG_BN_EPS)) +
                   (double)b[j];
        h[j] = y > 0.0 ? y : 0.0;
    }
#pragma unroll
    for (int o = 0; o < RG_OUT; ++o) {
        double acc = (double)bo2[o];
#pragma unroll
        for (int j = 0; j < RG_H; ++j) acc += h[j] * (double)Wo2[j * RG_OUT + o];
        table[k * RG_OUT + o] = (float)acc;
    }
}

__global__ void out_kernel(const unsigned char* __restrict__ st, const float* __restrict__ table,
                           float* __restrict__ out, int n) {
    int i = blockIdx.x * blockDim.x + threadIdx.x;
    if (i >= n) return;
    int s = (int)st[i];
    float4 a = ((const float4*)table)[s * 2];
    float4 b = ((const float4*)table)[s * 2 + 1];
    ((float4*)out)[(size_t)i * 2] = a;
    ((float4*)out)[(size_t)i * 2 + 1] = b;
}

// ---------------------------------------------------------------------------
extern "C" void kernel_launch(void* const* d_in, const int* in_sizes, int n_in,
                              void* d_out, int out_size, void* d_ws, size_t ws_size,
                              hipStream_t stream) {
    const float* x     = (const float*)d_in[0];
    const void*  ei    = d_in[1];
    const float* W_in  = (const float*)d_in[2];
    const float* b_in  = (const float*)d_in[3];
    const float* W_rec = (const float*)d_in[4];
    const float* b_rec = (const float*)d_in[5];
    const float* bn_g  = (const float*)d_in[6];
    const float* bn_b  = (const float*)d_in[7];
    const float* bn_m  = (const float*)d_in[8];
    const float* bn_v  = (const float*)d_in[9];
    const float* Wo1   = (const float*)d_in[10];
    const float* bo1   = (const float*)d_in[11];
    const float* bno_g = (const float*)d_in[12];
    const float* bno_b = (const float*)d_in[13];
    const float* bno_m = (const float*)d_in[14];
    const float* bno_v = (const float*)d_in[15];
    const float* Wo2   = (const float*)d_in[16];
    const float* bo2   = (const float*)d_in[17];

    int N = in_sizes[0] / RG_IN;
    int E = in_sizes[1] / 2;

    char* ws = (char*)d_ws;
    size_t off = 0;
    auto alloc = [&](size_t bytes) -> void* {
        void* p = ws + off;
        off = (off + bytes + 255) & ~(size_t)255;
        return p;
    };
    int nchunks = (N + 255) / 256;
    int*           flag    = (int*)alloc(sizeof(int));
    int*           deg     = (int*)alloc((size_t)N * sizeof(int));
    int*           row_off = (int*)alloc((size_t)(N + 1) * sizeof(int));
    int*           cursor  = (int*)alloc((size_t)N * sizeof(int));
    int*           adj     = (int*)alloc((size_t)E * sizeof(int));
    int*           srcs    = (int*)alloc((size_t)E * sizeof(int));
    int*           dsts    = (int*)alloc((size_t)E * sizeof(int));
    int*           bsum    = (int*)alloc((size_t)nchunks * sizeof(int));
    unsigned char* stA     = (unsigned char*)alloc((size_t)N);
    unsigned char* stB     = (unsigned char*)alloc((size_t)N);
    int*           ambc    = (int*)alloc(RG_ITERS * sizeof(int));
    int*           ambl    = (int*)alloc((size_t)N * sizeof(int));
    float*         table   = (float*)alloc(RG_S * RG_OUT * sizeof(float));

    hipMemsetAsync(deg, 0, (size_t)N * sizeof(int), stream);
    hipMemsetAsync(ambc, 0, RG_ITERS * sizeof(int), stream);
    detect_i64_kernel<<<1, 64, 0, stream>>>((const unsigned int*)ei, flag);

    compact_kernel<<<2048, 256, 0, stream>>>(ei, flag, srcs, dsts, E);
    deg2_kernel<<<4096, 256, 0, stream>>>(dsts, deg, E, N);
    scanA_kernel<<<nchunks, 256, 0, stream>>>(deg, bsum, N);
    scanB_kernel<<<1, 512, 0, stream>>>(bsum, row_off, nchunks, N);
    scanC_kernel<<<nchunks, 256, 0, stream>>>(deg, bsum, row_off, cursor, N);
    fill2_kernel<<<4096, 256, 0, stream>>>(srcs, dsts, cursor, adj, E, N);

    input_kernel<<<1280, 256, 0, stream>>>(x, W_in, b_in, stA, N);

    unsigned char* sin = stA;
    unsigned char* sout = stB;
    for (int it = 0; it < RG_ITERS; ++it) {
        iter_screen_kernel<<<1024, 256, 0, stream>>>(row_off, adj, sin, sout, W_rec, b_rec,
                                                     bn_g, bn_b, bn_m, bn_v,
                                                     ambc + it, ambl, N);
        iter_fix_kernel<<<128, 256, 0, stream>>>(ambc + it, ambl, row_off, adj, sin, sout,
                                                 W_rec, b_rec, bn_g, bn_b, bn_m, bn_v);
        unsigned char* t = sin; sin = sout; sout = t;
    }

    table_kernel<<<1, 64, 0, stream>>>(Wo1, bo1, bno_g, bno_b, bno_m, bno_v, Wo2, bo2, table);
    out_kernel<<<(N + 255) / 256, 256, 0, stream>>>(sin, table, (float*)d_out, N);
}

// Round 8
// 1121.270 us; speedup vs baseline: 2.3274x; 1.0192x over previous
//
#include <hip/hip_runtime.h>

#define RG_ITERS 12
#define RG_S 64
#define RG_IN 128
#define RG_H 16
#define RG_OUT 8
#define RG_BN_EPS 1e-5
#define RG_IN_THRESH 2e-3f   // f32 screen gap threshold, input layer (err bound ~1e-5)
#define RG_IT_THRESH 5e-4f   // f32 screen gap threshold, recurrent layer (err bound ~2e-5)

// ---------------------------------------------------------------------------
// Detect whether edge_index buffer is int64 (odd int32 words all zero) or int32
// ---------------------------------------------------------------------------
__global__ void detect_i64_kernel(const unsigned int* __restrict__ ei32, int* __restrict__ flag) {
    if (blockIdx.x == 0 && threadIdx.x == 0) {
        int allz = 1;
        for (int i = 1; i < 64; i += 2) allz &= (ei32[i] == 0u);
        *flag = allz;  // 1 -> int64, 0 -> int32
    }
}

// Compact edge list to int32 src/dst streams (handles i64 or i32 input)
__global__ void compact_kernel(const void* __restrict__ ei, const int* __restrict__ flag,
                               int* __restrict__ srcs, int* __restrict__ dsts, int E) {
    int is64 = *flag;
    int stride = gridDim.x * blockDim.x;
    for (int i = blockIdx.x * blockDim.x + threadIdx.x; i < E; i += stride) {
        int sv, dv;
        if (is64) {
            sv = (int)__builtin_nontemporal_load(&((const long long*)ei)[i]);
            dv = (int)__builtin_nontemporal_load(&((const long long*)ei)[(long long)E + i]);
        } else {
            sv = __builtin_nontemporal_load(&((const int*)ei)[i]);
            dv = __builtin_nontemporal_load(&((const int*)ei)[(long long)E + i]);
        }
        __builtin_nontemporal_store(sv, &srcs[i]);
        __builtin_nontemporal_store(dv, &dsts[i]);
    }
}

// ---------------------------------------------------------------------------
// CSR build, L2-windowed: class r = blockIdx&7 (round-robin -> XCD r) owns
// dst range [r*span, (r+1)*span). Scatter targets stay in that XCD's L2.
// Streaming reads are non-temporal so they don't evict the window.
// ---------------------------------------------------------------------------
__global__ __launch_bounds__(256) void deg2_kernel(const int* __restrict__ dsts,
                                                   int* __restrict__ deg, int E, int N) {
    int r = blockIdx.x & 7;
    int nb = gridDim.x >> 3;
    int bi = blockIdx.x >> 3;
    int span = (N + 7) >> 3;
    int lo = r * span;
    int hi = lo + span; hi = hi < N ? hi : N;
    int stride = nb * 256;
    for (int i = bi * 256 + threadIdx.x; i < E; i += stride) {
        int d = __builtin_nontemporal_load(&dsts[i]);
        if (d >= lo && d < hi) atomicAdd(&deg[d], 1);
    }
}

__global__ __launch_bounds__(256) void fill2_kernel(const int* __restrict__ srcs,
                                                    const int* __restrict__ dsts,
                                                    int* __restrict__ cursor,
                                                    int* __restrict__ adj, int E, int N) {
    int r = blockIdx.x & 7;
    int nb = gridDim.x >> 3;
    int bi = blockIdx.x >> 3;
    int span = (N + 7) >> 3;
    int lo = r * span;
    int hi = lo + span; hi = hi < N ? hi : N;
    int stride = nb * 256;
    for (int i = bi * 256 + threadIdx.x; i < E; i += stride) {
        int d = __builtin_nontemporal_load(&dsts[i]);
        if (d >= lo && d < hi) {
            int sv = __builtin_nontemporal_load(&srcs[i]);
            int p = atomicAdd(&cursor[d], 1);
            adj[p] = sv;  // row order nondeterministic; counting is order-invariant
        }
    }
}

// per-256-chunk sums
__global__ __launch_bounds__(256) void scanA_kernel(const int* __restrict__ deg,
                                                    int* __restrict__ bsum, int n) {
    int i = blockIdx.x * 256 + threadIdx.x;
    int v = (i < n) ? deg[i] : 0;
#pragma unroll
    for (int off = 32; off; off >>= 1) v += __shfl_xor(v, off);
    __shared__ int ws[4];
    if ((threadIdx.x & 63) == 0) ws[threadIdx.x >> 6] = v;
    __syncthreads();
    if (threadIdx.x == 0) bsum[blockIdx.x] = ws[0] + ws[1] + ws[2] + ws[3];
}

// exclusive scan of block sums, single block w/ carry loop
__global__ __launch_bounds__(512) void scanB_kernel(int* __restrict__ bsum,
                                                    int* __restrict__ row_off, int nb, int n) {
    __shared__ int buf[512];
    __shared__ int carry;
    int tid = threadIdx.x;
    if (tid == 0) carry = 0;
    __syncthreads();
    for (int base = 0; base < nb; base += 512) {
        int i = base + tid;
        int v = (i < nb) ? bsum[i] : 0;
        buf[tid] = v;
        __syncthreads();
        for (int off = 1; off < 512; off <<= 1) {
            int t = (tid >= off) ? buf[tid - off] : 0;
            __syncthreads();
            buf[tid] += t;
            __syncthreads();
        }
        if (i < nb) bsum[i] = carry + buf[tid] - v;  // exclusive
        __syncthreads();
        if (tid == 0) carry += buf[511];
        __syncthreads();
    }
    if (tid == 0) row_off[n] = carry;  // total edge count
}

// re-scan each 256-chunk, add block offset, emit row_off + cursor
__global__ __launch_bounds__(256) void scanC_kernel(const int* __restrict__ deg,
                                                    const int* __restrict__ bsum,
                                                    int* __restrict__ row_off,
                                                    int* __restrict__ cursor, int n) {
    __shared__ int buf[256];
    int tid = threadIdx.x;
    int i = blockIdx.x * 256 + tid;
    int v = (i < n) ? deg[i] : 0;
    buf[tid] = v;
    __syncthreads();
    for (int off = 1; off < 256; off <<= 1) {
        int t = (tid >= off) ? buf[tid - off] : 0;
        __syncthreads();
        buf[tid] += t;
        __syncthreads();
    }
    if (i < n) {
        int e = bsum[blockIdx.x] + buf[tid] - v;
        row_off[i] = e;
        cursor[i] = e;
    }
}

// ---------------------------------------------------------------------------
// Wave top-2 merge butterfly: returns (v1,i1,v2) identical in all lanes.
// Tie-break: smaller index wins top1 (matches jnp.argmax).
// ---------------------------------------------------------------------------
__device__ __forceinline__ void top2_f32(float y, int lane, float& v1, int& i1, float& v2) {
    v1 = y; i1 = lane; v2 = -3.4e38f;
#pragma unroll
    for (int off = 32; off; off >>= 1) {
        float ov1 = __shfl_xor(v1, off);
        int oi1 = __shfl_xor(i1, off);
        float ov2 = __shfl_xor(v2, off);
        bool take = (ov1 > v1) || (ov1 == v1 && oi1 < i1);
        float nv2 = take ? fmaxf(v1, ov2) : fmaxf(v2, ov1);
        v1 = take ? ov1 : v1;
        i1 = take ? oi1 : i1;
        v2 = nv2;
    }
}

__device__ __forceinline__ int argmax_f64(double y, int lane) {
    double best = y;
    int bi = lane;
#pragma unroll
    for (int off = 32; off; off >>= 1) {
        double ov = __shfl_xor(best, off);
        int oi = __shfl_xor(bi, off);
        if (ov > best || (ov == best && oi < bi)) { best = ov; bi = oi; }
    }
    return bi;
}

// ---------------------------------------------------------------------------
// Full-wave ballot histogram (cold path): cnt = #in-neighbors state==lane, <=10
// ---------------------------------------------------------------------------
__device__ __forceinline__ int hist_count(const int* __restrict__ adj,
                                          const unsigned char* __restrict__ st_in,
                                          int beg, int end, int lane) {
    int cnt = 0;
    for (int base = beg; base < end; base += 64) {
        int idx = base + lane;
        unsigned long long valid = __ballot(idx < end);
        int sv = (idx < end) ? (int)st_in[adj[idx]] : 0;
        unsigned long long mm = valid;
#pragma unroll
        for (int b = 0; b < 6; ++b) {
            unsigned long long bl = __ballot(((sv >> b) & 1) != 0);
            mm &= ((lane >> b) & 1) ? bl : ~bl;
        }
        cnt += (int)__popcll(mm);
    }
    return cnt > 10 ? 10 : cnt;
}

// Byte butterfly pack (cold path only): count -> pk[16] bytes
__device__ __forceinline__ void pack_bytes(unsigned cmin, int lane, unsigned pk[16]) {
    unsigned v = cmin, p;
    p = __shfl_xor(v, 1); v = (lane & 1) ? (p | (v << 8)) : (v | (p << 8));
    p = __shfl_xor(v, 2); v = (lane & 2) ? (p | (v << 16)) : (v | (p << 16));
    unsigned q0, q1;
    p = __shfl_xor(v, 4); q0 = (lane & 4) ? p : v; q1 = (lane & 4) ? v : p;
    unsigned r0 = __shfl_xor(q0, 8), r1 = __shfl_xor(q1, 8);
    unsigned u0, u1, u2, u3;
    if (lane & 8) { u0 = r0; u1 = r1; u2 = q0; u3 = q1; }
    else          { u0 = q0; u1 = q1; u2 = r0; u3 = r1; }
    unsigned w0 = __shfl_xor(u0, 16), w1 = __shfl_xor(u1, 16),
             w2 = __shfl_xor(u2, 16), w3 = __shfl_xor(u3, 16);
    unsigned a0, a1, a2, a3, a4, a5, a6, a7;
    if (lane & 16) { a0 = w0; a1 = w1; a2 = w2; a3 = w3; a4 = u0; a5 = u1; a6 = u2; a7 = u3; }
    else           { a0 = u0; a1 = u1; a2 = u2; a3 = u3; a4 = w0; a5 = w1; a6 = w2; a7 = w3; }
    unsigned b0 = __shfl_xor(a0, 32), b1 = __shfl_xor(a1, 32), b2 = __shfl_xor(a2, 32),
             b3 = __shfl_xor(a3, 32), b4 = __shfl_xor(a4, 32), b5 = __shfl_xor(a5, 32),
             b6 = __shfl_xor(a6, 32), b7 = __shfl_xor(a7, 32);
    if (lane & 32) {
        pk[0] = b0; pk[1] = b1; pk[2] = b2; pk[3] = b3;
        pk[4] = b4; pk[5] = b5; pk[6] = b6; pk[7] = b7;
        pk[8] = a0; pk[9] = a1; pk[10] = a2; pk[11] = a3;
        pk[12] = a4; pk[13] = a5; pk[14] = a6; pk[15] = a7;
    } else {
        pk[0] = a0; pk[1] = a1; pk[2] = a2; pk[3] = a3;
        pk[4] = a4; pk[5] = a5; pk[6] = a6; pk[7] = a7;
        pk[8] = b0; pk[9] = b1; pk[10] = b2; pk[11] = b3;
        pk[12] = b4; pk[13] = b5; pk[14] = b6; pk[15] = b7;
    }
}

// ---------------------------------------------------------------------------
// Input layer: 8 nodes per wave iteration. Each LDS weight read feeds 8 FMAs;
// 32 independent f32 chains, 8 in-flight broadcast load streams.
// f64 fallback per node if top-2 gap < THRESH (rare, wave-uniform).
// ---------------------------------------------------------------------------
__device__ __forceinline__ int input_f64_node(const float4* __restrict__ xr,
                                              const float* __restrict__ wsh,
                                              double bind, int lane) {
    double a0 = 0.0, a1 = 0.0, a2 = 0.0, a3 = 0.0;
#pragma unroll 8
    for (int k4 = 0; k4 < RG_IN / 4; ++k4) {
        float4 xv = xr[k4];
        int k = k4 * 4;
        a0 += (double)xv.x * (double)wsh[(k + 0) * RG_S + lane];
        a1 += (double)xv.y * (double)wsh[(k + 1) * RG_S + lane];
        a2 += (double)xv.z * (double)wsh[(k + 2) * RG_S + lane];
        a3 += (double)xv.w * (double)wsh[(k + 3) * RG_S + lane];
    }
    double acc = bind + ((a0 + a2) + (a1 + a3));
    return argmax_f64(acc, lane);
}

__global__ __launch_bounds__(256) void input_kernel(const float* __restrict__ x,
                                                    const float* __restrict__ W_in,
                                                    const float* __restrict__ b_in,
                                                    unsigned char* __restrict__ st, int n) {
    __shared__ float wsh[RG_IN * RG_S];  // 32 KB
    for (int i = threadIdx.x; i < RG_IN * RG_S; i += 256) wsh[i] = W_in[i];
    __syncthreads();
    int lane = threadIdx.x & 63;
    int wid = threadIdx.x >> 6;
    float binf = b_in[lane];
    double bind = (double)binf;
    int wave = blockIdx.x * 4 + wid;
    int nwaves = gridDim.x * 4;
    int ngroups = (n + 7) >> 3;
    for (int g = wave; g < ngroups; g += nwaves) {
        int base = g * 8;
        int nd[8];
        const float4* xp[8];
#pragma unroll
        for (int j = 0; j < 8; ++j) {
            int nj = base + j;
            nd[j] = nj < n ? nj : n - 1;
            xp[j] = (const float4*)(x + (size_t)nd[j] * RG_IN);
        }
        float acc[8][4];
#pragma unroll
        for (int j = 0; j < 8; ++j)
#pragma unroll
            for (int c = 0; c < 4; ++c) acc[j][c] = 0.f;
#pragma unroll 2
        for (int k4 = 0; k4 < RG_IN / 4; ++k4) {
            int k = k4 * 4;
            float w0 = wsh[(k + 0) * RG_S + lane];
            float w1 = wsh[(k + 1) * RG_S + lane];
            float w2 = wsh[(k + 2) * RG_S + lane];
            float w3 = wsh[(k + 3) * RG_S + lane];
#pragma unroll
            for (int j = 0; j < 8; ++j) {
                float4 v = xp[j][k4];
                acc[j][0] += v.x * w0;
                acc[j][1] += v.y * w1;
                acc[j][2] += v.z * w2;
                acc[j][3] += v.w * w3;
            }
        }
        int sres[8];
#pragma unroll
        for (int j = 0; j < 8; ++j) {
            float y = ((acc[j][0] + acc[j][2]) + (acc[j][1] + acc[j][3])) + binf;
            float v1f, v2f;
            int i1;
            top2_f32(y, lane, v1f, i1, v2f);
            sres[j] = (v1f - v2f < RG_IN_THRESH) ? input_f64_node(xp[j], wsh, bind, lane) : i1;
        }
        if (lane == 0) {
#pragma unroll
            for (int j = 0; j < 8; ++j) st[nd[j]] = (unsigned char)sres[j];
        }
    }
}

// ---------------------------------------------------------------------------
// Recurrent iteration, phase 1 (hot): f32 screen, 2 nodes per wave iteration.
// HALF-WAVE gather: lanes 0-31 load node A's edges, lanes 32-63 node B's;
// one 6-ballot sieve yields BOTH histograms (lo/hi 32 bits of the mask).
// Counts broadcast via per-wave LDS slot. BN pre-folded into weights.
// Ambiguous waves append node to list for exact-f64 phase 2.
// ---------------------------------------------------------------------------
__global__ __launch_bounds__(256) void iter_screen_kernel(
    const int* __restrict__ row_off, const int* __restrict__ adj,
    const unsigned char* __restrict__ st_in, unsigned char* __restrict__ st_out,
    const float* __restrict__ W_rec, const float* __restrict__ b_rec,
    const float* __restrict__ bn_g, const float* __restrict__ bn_b,
    const float* __restrict__ bn_m, const float* __restrict__ bn_v,
    int* __restrict__ amb_cnt, int* __restrict__ amb_list, int n) {
    __shared__ unsigned int cslot[4][2][16];  // [wave][node A/B][64 byte counts]
    int lane = threadIdx.x & 63;
    int wid = threadIdx.x >> 6;
    int sub = lane & 31;
    bool hiHalf = lane >= 32;

    float s = bn_g[lane] * rsqrtf(bn_v[lane] + 1e-5f);
    float biasp = b_rec[lane] * s + (bn_b[lane] - bn_m[lane] * s);
    float wcol[RG_S];
#pragma unroll
    for (int k = 0; k < RG_S; ++k) wcol[k] = W_rec[k * RG_S + lane] * s;

    unsigned char* slotA = (unsigned char*)&cslot[wid][0][0];
    unsigned char* slotB = (unsigned char*)&cslot[wid][1][0];

    int wave = blockIdx.x * 4 + wid;
    int nwaves = gridDim.x * 4;
    for (int nA = wave; nA < n; nA += 2 * nwaves) {
        int nB = nA + nwaves;
        bool hasB = nB < n;
        int nBc = hasB ? nB : nA;
        int begA = row_off[nA], endA = row_off[nA + 1];
        int begB = row_off[nBc], endB = row_off[nBc + 1];
        int stoA = (int)st_in[nA];
        int stoB = (int)st_in[nBc];
        float wselfA = W_rec[(RG_S + stoA) * RG_S + lane] * s;
        float wselfB = W_rec[(RG_S + stoB) * RG_S + lane] * s;

        int myBeg = hiHalf ? begB : begA;
        int myDeg = hiHalf ? (endB - begB) : (endA - begA);
        int dA = endA - begA, dB = endB - begB;
        int dmax = dA > dB ? dA : dB;
        int cntA = 0, cntB = 0;
        for (int base = 0; base < dmax; base += 32) {
            int off = base + sub;
            bool v = off < myDeg;
            unsigned long long valid = __ballot(v);
            int sv = v ? (int)st_in[adj[myBeg + off]] : 0;
            unsigned long long mm = valid;
#pragma unroll
            for (int b = 0; b < 6; ++b) {
                unsigned long long bl = __ballot(((sv >> b) & 1) != 0);
                mm &= ((lane >> b) & 1) ? bl : ~bl;
            }
            cntA += (int)__popcll(mm & 0xFFFFFFFFull);
            cntB += (int)__popcll(mm >> 32);
        }
        slotA[lane] = (unsigned char)(cntA > 10 ? 10 : cntA);
        slotB[lane] = (unsigned char)(cntB > 10 ? 10 : cntB);

        // same-wave DS ordering: all lanes' byte writes precede these reads
        float yA0 = 0.f, yA1 = 0.f, yA2 = 0.f, yA3 = 0.f;
        float yB0 = 0.f, yB1 = 0.f, yB2 = 0.f, yB3 = 0.f;
#pragma unroll
        for (int g = 0; g < 16; ++g) {
            unsigned pA = cslot[wid][0][g];
            unsigned pB = cslot[wid][1][g];
            yA0 += (float)(pA & 0xFFu)         * wcol[4 * g + 0];
            yA1 += (float)((pA >> 8) & 0xFFu)  * wcol[4 * g + 1];
            yA2 += (float)((pA >> 16) & 0xFFu) * wcol[4 * g + 2];
            yA3 += (float)(pA >> 24)           * wcol[4 * g + 3];
            yB0 += (float)(pB & 0xFFu)         * wcol[4 * g + 0];
            yB1 += (float)((pB >> 8) & 0xFFu)  * wcol[4 * g + 1];
            yB2 += (float)((pB >> 16) & 0xFFu) * wcol[4 * g + 2];
            yB3 += (float)(pB >> 24)           * wcol[4 * g + 3];
        }
        float yA = ((yA0 + yA2) + (yA1 + yA3)) + biasp + wselfA;
        float v1, v2;
        int i1;
        top2_f32(yA, lane, v1, i1, v2);
        if (lane == 0) {
            st_out[nA] = (unsigned char)i1;
            if (v1 - v2 < RG_IT_THRESH) {
                int pidx = atomicAdd(amb_cnt, 1);
                amb_list[pidx] = nA;
            }
        }
        if (hasB) {
            float yB = ((yB0 + yB2) + (yB1 + yB3)) + biasp + wselfB;
            top2_f32(yB, lane, v1, i1, v2);
            if (lane == 0) {
                st_out[nB] = (unsigned char)i1;
                if (v1 - v2 < RG_IT_THRESH) {
                    int pidx = atomicAdd(amb_cnt, 1);
                    amb_list[pidx] = nB;
                }
            }
        }
    }
}

// ---------------------------------------------------------------------------
// Recurrent iteration, phase 2 (rare): exact f64 recompute for listed nodes.
// ---------------------------------------------------------------------------
__global__ __launch_bounds__(256) void iter_fix_kernel(
    const int* __restrict__ amb_cnt, const int* __restrict__ amb_list,
    const int* __restrict__ row_off, const int* __restrict__ adj,
    const unsigned char* __restrict__ st_in, unsigned char* __restrict__ st_out,
    const float* __restrict__ W_rec, const float* __restrict__ b_rec,
    const float* __restrict__ bn_g, const float* __restrict__ bn_b,
    const float* __restrict__ bn_m, const float* __restrict__ bn_v) {
    int tot = *amb_cnt;
    if (tot <= 0) return;
    int lane = threadIdx.x & 63;
    int wid = threadIdx.x >> 6;
    double brec = (double)b_rec[lane];
    double bnm = (double)bn_m[lane];
    double bns = (double)bn_g[lane] / sqrt((double)bn_v[lane] + RG_BN_EPS);
    double bnb = (double)bn_b[lane];
    int nw = gridDim.x * 4;
    for (int li = blockIdx.x * 4 + wid; li < tot; li += nw) {
        int node = amb_list[li];
        int beg = row_off[node], end = row_off[node + 1];
        int st_old = (int)st_in[node];
        float wself = W_rec[(RG_S + st_old) * RG_S + lane];
        int cmin = hist_count(adj, st_in, beg, end, lane);
        unsigned pk[16];
        pack_bytes((unsigned)cmin, lane, pk);
        double z0 = 0.0, z1 = 0.0, z2 = 0.0, z3 = 0.0;
#pragma unroll
        for (int g = 0; g < 16; ++g) {
            unsigned pg = pk[g];
            z0 += (double)(pg & 0xFFu)         * (double)W_rec[(4 * g + 0) * RG_S + lane];
            z1 += (double)((pg >> 8) & 0xFFu)  * (double)W_rec[(4 * g + 1) * RG_S + lane];
            z2 += (double)((pg >> 16) & 0xFFu) * (double)W_rec[(4 * g + 2) * RG_S + lane];
            z3 += (double)(pg >> 24)           * (double)W_rec[(4 * g + 3) * RG_S + lane];
        }
        double z = ((z0 + z2) + (z1 + z3)) + brec + (double)wself;
        double y = (z - bnm) * bns + bnb;
        int st_res = argmax_f64(y, lane);
        if (lane == 0) st_out[node] = (unsigned char)st_res;
    }
}

// ---------------------------------------------------------------------------
// Output MLP collapses to a 64x8 lookup table over the final state
// ---------------------------------------------------------------------------
__global__ void table_kernel(const float* __restrict__ Wo1, const float* __restrict__ bo1,
                             const float* __restrict__ g, const float* __restrict__ b,
                             const float* __restrict__ m, const float* __restrict__ v,
                             const float* __restrict__ Wo2, const float* __restrict__ bo2,
                             float* __restrict__ table) {
    int k = threadIdx.x;
    if (k >= RG_S) return;
    double h[RG_H];
#pragma unroll
    for (int j = 0; j < RG_H; ++j) {
        double z = (double)Wo1[k * RG_H + j] + (double)bo1[j];
        double y = (z - (double)m[j]) * ((double)g[j] / sqrt((double)v[j] + RG_BN_EPS)) +
                   (double)b[j];
        h[j] = y > 0.0 ? y : 0.0;
    }
#pragma unroll
    for (int o = 0; o < RG_OUT; ++o) {
        double acc = (double)bo2[o];
#pragma unroll
        for (int j = 0; j < RG_H; ++j) acc += h[j] * (double)Wo2[j * RG_OUT + o];
        table[k * RG_OUT + o] = (float)acc;
    }
}

__global__ void out_kernel(const unsigned char* __restrict__ st, const float* __restrict__ table,
                           float* __restrict__ out, int n) {
    int i = blockIdx.x * blockDim.x + threadIdx.x;
    if (i >= n) return;
    int s = (int)st[i];
    float4 a = ((const float4*)table)[s * 2];
    float4 b = ((const float4*)table)[s * 2 + 1];
    ((float4*)out)[(size_t)i * 2] = a;
    ((float4*)out)[(size_t)i * 2 + 1] = b;
}

// ---------------------------------------------------------------------------
extern "C" void kernel_launch(void* const* d_in, const int* in_sizes, int n_in,
                              void* d_out, int out_size, void* d_ws, size_t ws_size,
                              hipStream_t stream) {
    const float* x     = (const float*)d_in[0];
    const void*  ei    = d_in[1];
    const float* W_in  = (const float*)d_in[2];
    const float* b_in  = (const float*)d_in[3];
    const float* W_rec = (const float*)d_in[4];
    const float* b_rec = (const float*)d_in[5];
    const float* bn_g  = (const float*)d_in[6];
    const float* bn_b  = (const float*)d_in[7];
    const float* bn_m  = (const float*)d_in[8];
    const float* bn_v  = (const float*)d_in[9];
    const float* Wo1   = (const float*)d_in[10];
    const float* bo1   = (const float*)d_in[11];
    const float* bno_g = (const float*)d_in[12];
    const float* bno_b = (const float*)d_in[13];
    const float* bno_m = (const float*)d_in[14];
    const float* bno_v = (const float*)d_in[15];
    const float* Wo2   = (const float*)d_in[16];
    const float* bo2   = (const float*)d_in[17];

    int N = in_sizes[0] / RG_IN;
    int E = in_sizes[1] / 2;

    char* ws = (char*)d_ws;
    size_t off = 0;
    auto alloc = [&](size_t bytes) -> void* {
        void* p = ws + off;
        off = (off + bytes + 255) & ~(size_t)255;
        return p;
    };
    int nchunks = (N + 255) / 256;
    int*           flag    = (int*)alloc(sizeof(int));
    int*           deg     = (int*)alloc((size_t)N * sizeof(int));
    int*           row_off = (int*)alloc((size_t)(N + 1) * sizeof(int));
    int*           cursor  = (int*)alloc((size_t)N * sizeof(int));
    int*           adj     = (int*)alloc((size_t)E * sizeof(int));
    int*           srcs    = (int*)alloc((size_t)E * sizeof(int));
    int*           dsts    = (int*)alloc((size_t)E * sizeof(int));
    int*           bsum    = (int*)alloc((size_t)nchunks * sizeof(int));
    unsigned char* stA     = (unsigned char*)alloc((size_t)N);
    unsigned char* stB     = (unsigned char*)alloc((size_t)N);
    int*           ambc    = (int*)alloc(RG_ITERS * sizeof(int));
    int*           ambl    = (int*)alloc((size_t)N * sizeof(int));
    float*         table   = (float*)alloc(RG_S * RG_OUT * sizeof(float));

    hipMemsetAsync(deg, 0, (size_t)N * sizeof(int), stream);
    hipMemsetAsync(ambc, 0, RG_ITERS * sizeof(int), stream);
    detect_i64_kernel<<<1, 64, 0, stream>>>((const unsigned int*)ei, flag);

    compact_kernel<<<2048, 256, 0, stream>>>(ei, flag, srcs, dsts, E);
    deg2_kernel<<<4096, 256, 0, stream>>>(dsts, deg, E, N);
    scanA_kernel<<<nchunks, 256, 0, stream>>>(deg, bsum, N);
    scanB_kernel<<<1, 512, 0, stream>>>(bsum, row_off, nchunks, N);
    scanC_kernel<<<nchunks, 256, 0, stream>>>(deg, bsum, row_off, cursor, N);
    fill2_kernel<<<4096, 256, 0, stream>>>(srcs, dsts, cursor, adj, E, N);

    input_kernel<<<1280, 256, 0, stream>>>(x, W_in, b_in, stA, N);

    unsigned char* sin = stA;
    unsigned char* sout = stB;
    for (int it = 0; it < RG_ITERS; ++it) {
        iter_screen_kernel<<<1024, 256, 0, stream>>>(row_off, adj, sin, sout, W_rec, b_rec,
                                                     bn_g, bn_b, bn_m, bn_v,
                                                     ambc + it, ambl, N);
        iter_fix_kernel<<<128, 256, 0, stream>>>(ambc + it, ambl, row_off, adj, sin, sout,
                                                 W_rec, b_rec, bn_g, bn_b, bn_m, bn_v);
        unsigned char* t = sin; sin = sout; sout = t;
    }

    table_kernel<<<1, 64, 0, stream>>>(Wo1, bo1, bno_g, bno_b, bno_m, bno_v, Wo2, bo2, table);
    out_kernel<<<(N + 255) / 256, 256, 0, stream>>>(sin, table, (float*)d_out, N);
}